// Round 1
// baseline (712.885 us; speedup 1.0000x reference)
//
#include <hip/hip_runtime.h>
#include <hip/hip_bf16.h>
#include <math.h>

#define BB 4
#define NN 126720
#define GG 32
#define CC 4
#define KK 1024
#define NBIN 16384
#define CANDMAX 4096
#define FG_TH 0.5f
#define NMS_TH 0.4f
#define EPSf 1e-6f

// ---- ws layout (bytes) ----
// accum[8] f32            @ 0        cls_sum, fg_sum, l2d_sum, l3d_sum, nms_sum
// cnt[B] u32              @ 32
// Tbin[B] u32             @ 48
// cand[B*CANDMAX] u64     @ 64       -> 64 + 131072 = 131136
// scores[B*N] f32         @ 131136   -> + 2027520 = 2158656
// hist[B*NBIN] u32        @ 2158656  -> + 262144 = 2420800
// sk[B*K] f32             @ 2420800  -> + 16384 = 2437184
// pred[B*K] float4        @ 2437184  -> + 65536 = 2502720
// aval[B*K] f32           @ 2502720  -> + 16384 = 2519104
// tgt[B*K] f32            @ 2519104  -> + 16384 = 2535488

__device__ inline float sl1(float x) {
    float ax = fabsf(x);
    return ax < 1.f ? 0.5f * ax * ax : ax - 1.f;
}

__device__ inline float iou44(const float4 a, const float4 b) {
    float aa = fmaxf(a.z - a.x, 0.f) * fmaxf(a.w - a.y, 0.f);
    float ab = fmaxf(b.z - b.x, 0.f) * fmaxf(b.w - b.y, 0.f);
    float w = fmaxf(fminf(a.z, b.z) - fmaxf(a.x, b.x), 0.f);
    float h = fmaxf(fminf(a.w, b.w) - fmaxf(a.y, b.y), 0.f);
    float inter = w * h;
    return inter / (aa + ab - inter + EPSf);
}

__global__ void init_kernel(float* accum, unsigned* cnt, unsigned* hist, float* tgt) {
    int i = blockIdx.x * 256 + threadIdx.x;
    if (i < BB * NBIN) hist[i] = 0u;
    if (i < BB * KK) tgt[i] = 0.f;
    if (i < 8) accum[i] = 0.f;
    if (i < BB) cnt[i] = 0u;
}

__global__ __launch_bounds__(256) void assign_kernel(
    const float* __restrict__ cls, const float* __restrict__ prob,
    const float* __restrict__ bbox2d, const float* __restrict__ bbox3d,
    const float* __restrict__ rois, const float* __restrict__ gtb,
    const int* __restrict__ gtl, const float* __restrict__ gt3,
    const float* __restrict__ means, const float* __restrict__ stds,
    float* accum, float* scores, unsigned* hist)
{
    __shared__ float s_gtb[GG * 4];
    __shared__ float s_gt3[GG * 7];
    __shared__ int s_gtl[GG];
    __shared__ float s_ms[22];   // [0..10] means, [11..21] stds
    int b = blockIdx.y;
    int tid = threadIdx.x;
    if (tid < GG * 4) s_gtb[tid] = gtb[b * GG * 4 + tid];
    if (tid < GG * 7) s_gt3[tid] = gt3[b * GG * 7 + tid];
    if (tid < GG) s_gtl[tid] = gtl[b * GG + tid];
    if (tid < 11) s_ms[tid] = means[tid];
    if (tid >= 32 && tid < 43) s_ms[11 + tid - 32] = stds[tid - 32];
    __syncthreads();

    int n = blockIdx.x * 256 + tid;
    float clsv = 0.f, fgv = 0.f, l2v = 0.f, l3v = 0.f;
    if (n < NN) {
        const float4 r = *(const float4*)(rois + (size_t)n * 4);
        float aa = fmaxf(r.z - r.x, 0.f) * fmaxf(r.w - r.y, 0.f);
        float best_iou = -1.f; int bg = 0;
        for (int g = 0; g < GG; ++g) {
            float gx1 = s_gtb[g * 4 + 0], gy1 = s_gtb[g * 4 + 1];
            float gx2 = s_gtb[g * 4 + 2], gy2 = s_gtb[g * 4 + 3];
            float ab = fmaxf(gx2 - gx1, 0.f) * fmaxf(gy2 - gy1, 0.f);
            float w = fmaxf(fminf(r.z, gx2) - fmaxf(r.x, gx1), 0.f);
            float h = fmaxf(fminf(r.w, gy2) - fmaxf(r.y, gy1), 0.f);
            float inter = w * h;
            float iou = inter / (aa + ab - inter + EPSf);
            if (iou > best_iou) { best_iou = iou; bg = g; }
        }
        bool fg = (best_iou >= FG_TH);

        // ---- cls loss ----
        const float4 c = *(const float4*)(cls + ((size_t)b * NN + n) * 4);
        float m = fmaxf(fmaxf(c.x, c.y), fmaxf(c.z, c.w));
        float lse = m + logf(expf(c.x - m) + expf(c.y - m) + expf(c.z - m) + expf(c.w - m));
        int label = fg ? s_gtl[bg] : 0;
        float csel = (label == 0) ? c.x : (label == 1) ? c.y : (label == 2) ? c.z : c.w;
        clsv = lse - csel;

        if (fg) {
            fgv = 1.f;
            float aw = r.z - r.x, ah = r.w - r.y;
            float acx = r.x + 0.5f * aw, acy = r.y + 0.5f * ah;
            float gx1 = s_gtb[bg * 4 + 0], gy1 = s_gtb[bg * 4 + 1];
            float gx2 = s_gtb[bg * 4 + 2], gy2 = s_gtb[bg * 4 + 3];
            float gw = gx2 - gx1, gh = gy2 - gy1;
            float gcx = gx1 + 0.5f * gw, gcy = gy1 + 0.5f * gh;
            float t0 = (gcx - acx) / (aw + EPSf);
            float t1 = (gcy - acy) / (ah + EPSf);
            float t2 = logf(gw / (aw + EPSf) + EPSf);
            float t3 = logf(gh / (ah + EPSf) + EPSf);
            t0 = (t0 - s_ms[0]) / s_ms[11];
            t1 = (t1 - s_ms[1]) / s_ms[12];
            t2 = (t2 - s_ms[2]) / s_ms[13];
            t3 = (t3 - s_ms[3]) / s_ms[14];
            const float4 d = *(const float4*)(bbox2d + ((size_t)b * NN + n) * 4);
            l2v = sl1(d.x - t0) + sl1(d.y - t1) + sl1(d.z - t2) + sl1(d.w - t3);
            const float* b3 = bbox3d + ((size_t)b * NN + n) * 7;
            for (int i = 0; i < 7; ++i) {
                float t = (s_gt3[bg * 7 + i] - s_ms[4 + i]) / s_ms[15 + i];
                l3v += sl1(b3[i] - t);
            }
        }

        // ---- NMS score ----
        const float4 p = *(const float4*)(prob + ((size_t)b * NN + n) * 4);
        float sc = fmaxf(fmaxf(p.y, p.z), p.w);
        scores[(size_t)b * NN + n] = sc;
        unsigned bin = __float_as_uint(sc) >> 16;
        if (bin >= NBIN) bin = NBIN - 1;
        atomicAdd(&hist[b * NBIN + bin], 1u);
    }
    // wave-level reduce, then atomics (all lanes alive)
    for (int o = 32; o; o >>= 1) {
        clsv += __shfl_down(clsv, o);
        fgv  += __shfl_down(fgv, o);
        l2v  += __shfl_down(l2v, o);
        l3v  += __shfl_down(l3v, o);
    }
    if ((tid & 63) == 0) {
        atomicAdd(&accum[0], clsv);
        atomicAdd(&accum[1], fgv);
        atomicAdd(&accum[2], l2v);
        atomicAdd(&accum[3], l3v);
    }
}

__global__ __launch_bounds__(1024) void thresh_kernel(const unsigned* __restrict__ hist, unsigned* Tbin) {
    __shared__ unsigned part[1024];
    int b = blockIdx.x, t = threadIdx.x;
    unsigned s = 0;
    for (int i = 0; i < 16; ++i) s += hist[b * NBIN + t * 16 + i];
    part[t] = s;
    __syncthreads();
    // Hillis-Steele suffix scan
    for (int off = 1; off < 1024; off <<= 1) {
        unsigned v = part[t] + ((t + off < 1024) ? part[t + off] : 0u);
        __syncthreads();
        part[t] = v;
        __syncthreads();
    }
    unsigned nxt = (t == 1023) ? 0u : part[t + 1];
    if (part[t] >= KK && nxt < KK) {
        unsigned cum = nxt;
        unsigned T = (unsigned)(t * 16);
        for (int i = 15; i >= 0; --i) {
            cum += hist[b * NBIN + t * 16 + i];
            if (cum >= KK) { T = (unsigned)(t * 16 + i); break; }
        }
        Tbin[b] = T;
    }
}

__global__ __launch_bounds__(256) void collect_kernel(
    const float* __restrict__ scores, const unsigned* __restrict__ Tbin,
    unsigned* cnt, unsigned long long* cand)
{
    int b = blockIdx.y;
    int n = blockIdx.x * 256 + threadIdx.x;
    if (n >= NN) return;
    unsigned bits = __float_as_uint(scores[(size_t)b * NN + n]);
    if ((bits >> 16) >= Tbin[b]) {
        unsigned pos = atomicAdd(&cnt[b], 1u);
        if (pos < CANDMAX)
            cand[b * CANDMAX + pos] = ((unsigned long long)bits << 32) | (unsigned)(~(unsigned)n);
    }
}

__global__ __launch_bounds__(1024) void sort_decode_kernel(
    const unsigned long long* __restrict__ cand, const unsigned* __restrict__ cnt,
    const float* __restrict__ bbox2d, const float* __restrict__ rois,
    const float* __restrict__ means, const float* __restrict__ stds,
    float* sk, float4* pred)
{
    __shared__ unsigned long long keys[CANDMAX];
    int b = blockIdx.x, t = threadIdx.x;
    unsigned c = cnt[b]; if (c > CANDMAX) c = CANDMAX;
    unsigned L = 1024; while (L < c) L <<= 1;
    for (unsigned i = t; i < L; i += 1024) keys[i] = (i < c) ? cand[b * CANDMAX + i] : 0ull;
    for (unsigned k = 2; k <= L; k <<= 1) {
        for (unsigned j = k >> 1; j > 0; j >>= 1) {
            __syncthreads();
            for (unsigned i = t; i < L; i += 1024) {
                unsigned ixj = i ^ j;
                if (ixj > i) {
                    unsigned long long a = keys[i], bb2 = keys[ixj];
                    bool up = ((i & k) == 0);
                    if (up ? (a < bb2) : (a > bb2)) { keys[i] = bb2; keys[ixj] = a; }
                }
            }
        }
    }
    __syncthreads();
    if (t < KK) {
        unsigned long long key = keys[t];
        float sc = __uint_as_float((unsigned)(key >> 32));
        unsigned n = ~((unsigned)key);
        if (n >= NN) n = NN - 1;   // safety (cnt>=K by construction)
        const float4 d = *(const float4*)(bbox2d + ((size_t)b * NN + n) * 4);
        const float4 r = *(const float4*)(rois + (size_t)n * 4);
        float d0 = d.x * stds[0] + means[0];
        float d1 = d.y * stds[1] + means[1];
        float d2 = d.z * stds[2] + means[2];
        float d3 = d.w * stds[3] + means[3];
        float aw = r.z - r.x, ah = r.w - r.y;
        float pcx = r.x + 0.5f * aw + d0 * aw;
        float pcy = r.y + 0.5f * ah + d1 * ah;
        float pw = aw * expf(fminf(fmaxf(d2, -4.f), 4.f));
        float ph = ah * expf(fminf(fmaxf(d3, -4.f), 4.f));
        pred[b * KK + t] = make_float4(pcx - 0.5f * pw, pcy - 0.5f * ph,
                                       pcx + 0.5f * pw, pcy + 0.5f * ph);
        sk[b * KK + t] = sc;
    }
}

__global__ __launch_bounds__(1024) void solve_kernel(
    const float4* __restrict__ pred, const float* __restrict__ sk, float* aval)
{
    __shared__ float4 bx[KK];
    __shared__ float a_sh[KK];
    __shared__ float ldiag[64 * 65];
    int b = blockIdx.x, t = threadIdx.x;
    int wave = t >> 6, lane = t & 63;
    float4 box = pred[b * KK + t];
    float sv = sk[b * KK + t];
    bx[t] = box;
    __syncthreads();
    float partial = 0.f;
    for (int blk = 0; blk < 16; ++blk) {
        int base = blk << 6;
        // parallel precompute of diag-block L entries (strict lower, thresholded)
        for (int q = 0; q < 4; ++q) {
            int e = t + (q << 10);
            int i = e >> 6, j = e & 63;
            float v = 0.f;
            if (i > j) {
                float iou = iou44(bx[base + i], bx[base + j]);
                v = (iou > NMS_TH) ? iou : 0.f;
            }
            ldiag[i * 65 + j] = v;
        }
        __syncthreads();
        if (wave == blk) {
            for (int jl = 0; jl < 64; ++jl) {
                float av = sv - partial;
                float aj = __shfl(av, jl);
                partial += ldiag[lane * 65 + jl] * aj;   // zero for lane<=jl
            }
            a_sh[base + lane] = sv - partial;
        }
        __syncthreads();
        if (wave > blk) {
            for (int jl = 0; jl < 64; ++jl) {
                int j = base + jl;
                float iou = iou44(box, bx[j]);
                float Lv = (iou > NMS_TH) ? iou : 0.f;
                partial += Lv * a_sh[j];
            }
        }
    }
    float a = sv - partial;
    aval[b * KK + t] = fminf(fmaxf(a, 0.f), 1.f);
}

__global__ __launch_bounds__(256) void best_kernel(
    const float4* __restrict__ pred, const float* __restrict__ gtb, float* tgt)
{
    int wid = blockIdx.x * 4 + (threadIdx.x >> 6);
    int lane = threadIdx.x & 63;
    int b = wid / GG, g = wid % GG;
    const float* gp = gtb + (b * GG + g) * 4;
    float gx1 = gp[0], gy1 = gp[1], gx2 = gp[2], gy2 = gp[3];
    float ab = fmaxf(gx2 - gx1, 0.f) * fmaxf(gy2 - gy1, 0.f);
    float bi = -1.f; int bk = 0;
    for (int k = lane; k < KK; k += 64) {
        float4 p = pred[b * KK + k];
        float aa = fmaxf(p.z - p.x, 0.f) * fmaxf(p.w - p.y, 0.f);
        float w = fmaxf(fminf(p.z, gx2) - fmaxf(p.x, gx1), 0.f);
        float h = fmaxf(fminf(p.w, gy2) - fmaxf(p.y, gy1), 0.f);
        float inter = w * h;
        float iou = inter / (aa + ab - inter + EPSf);
        if (iou > bi) { bi = iou; bk = k; }   // strictly greater: first-max kept
    }
    for (int o = 32; o; o >>= 1) {
        float oi = __shfl_down(bi, o);
        int ok = __shfl_down(bk, o);
        if (oi > bi || (oi == bi && ok < bk)) { bi = oi; bk = ok; }
    }
    if (lane == 0) tgt[b * KK + bk] = 1.f;
}

__global__ __launch_bounds__(1024) void bce_kernel(
    const float* __restrict__ aval, const float* __restrict__ tgt, float* accum)
{
    int i = blockIdx.x * 1024 + threadIdx.x;
    float v = 0.f;
    if (i < BB * KK) {
        float a = aval[i], tg = tgt[i];
        v = -(tg * logf(a + EPSf) + (1.f - tg) * logf(1.f - a + EPSf));
    }
    for (int o = 32; o; o >>= 1) v += __shfl_down(v, o);
    if ((threadIdx.x & 63) == 0) atomicAdd(&accum[4], v);
}

__global__ void finalize_kernel(const float* __restrict__ accum, float* out) {
    if (threadIdx.x == 0 && blockIdx.x == 0) {
        float nfg = fmaxf(accum[1], 1.f);
        out[0] = accum[0] / (float)(BB * NN)
               + accum[2] / nfg
               + accum[3] / nfg
               + accum[4] / (float)(BB * KK);
    }
}

extern "C" void kernel_launch(void* const* d_in, const int* in_sizes, int n_in,
                              void* d_out, int out_size, void* d_ws, size_t ws_size,
                              hipStream_t stream) {
    const float* cls    = (const float*)d_in[0];
    const float* prob   = (const float*)d_in[1];
    const float* bbox2d = (const float*)d_in[2];
    const float* bbox3d = (const float*)d_in[3];
    const float* rois   = (const float*)d_in[4];
    const float* gtb    = (const float*)d_in[5];
    const int*   gtl    = (const int*)d_in[6];
    const float* gt3    = (const float*)d_in[7];
    const float* means  = (const float*)d_in[8];
    const float* stds   = (const float*)d_in[9];
    float* out = (float*)d_out;
    char* ws = (char*)d_ws;

    float*              accum  = (float*)(ws + 0);
    unsigned*           cnt    = (unsigned*)(ws + 32);
    unsigned*           Tbin   = (unsigned*)(ws + 48);
    unsigned long long* cand   = (unsigned long long*)(ws + 64);
    float*              scores = (float*)(ws + 131136);
    unsigned*           hist   = (unsigned*)(ws + 2158656);
    float*              sk     = (float*)(ws + 2420800);
    float4*             pred   = (float4*)(ws + 2437184);
    float*              aval   = (float*)(ws + 2502720);
    float*              tgt    = (float*)(ws + 2519104);

    init_kernel<<<dim3(256), dim3(256), 0, stream>>>(accum, cnt, hist, tgt);

    dim3 gBN((NN + 255) / 256, BB);
    assign_kernel<<<gBN, dim3(256), 0, stream>>>(cls, prob, bbox2d, bbox3d, rois,
                                                 gtb, gtl, gt3, means, stds,
                                                 accum, scores, hist);
    thresh_kernel<<<dim3(BB), dim3(1024), 0, stream>>>(hist, Tbin);
    collect_kernel<<<gBN, dim3(256), 0, stream>>>(scores, Tbin, cnt, cand);
    sort_decode_kernel<<<dim3(BB), dim3(1024), 0, stream>>>(cand, cnt, bbox2d, rois,
                                                            means, stds, sk, pred);
    solve_kernel<<<dim3(BB), dim3(1024), 0, stream>>>(pred, sk, aval);
    best_kernel<<<dim3((BB * GG) / 4), dim3(256), 0, stream>>>(pred, gtb, tgt);
    bce_kernel<<<dim3((BB * KK + 1023) / 1024), dim3(1024), 0, stream>>>(aval, tgt, accum);
    finalize_kernel<<<dim3(1), dim3(64), 0, stream>>>(accum, out);
}

// Round 2
// 340.253 us; speedup vs baseline: 2.0952x; 2.0952x over previous
//
#include <hip/hip_runtime.h>
#include <hip/hip_bf16.h>
#include <math.h>

#define BB 4
#define NN 126720
#define GG 32
#define CC 4
#define KK 1024
#define NBIN 16384
#define CANDMAX 4096
#define NBLKX 495            // NN / 256 exactly
#define NBLK (NBLKX * BB)    // 1980
#define FG_TH 0.5f
#define NMS_TH 0.4f
#define EPSf 1e-6f

// ---- ws layout (bytes) ----
// accum[8] f32            @ 0
// cnt[B] u32              @ 32
// Tbin[B] u32             @ 48
// cand[B*CANDMAX] u64     @ 64       -> 131136
// scores[B*N] f32         @ 131136   -> 2158656
// sk[B*K] f32             @ 2158656  -> 2175040
// pred[B*K] float4        @ 2175040  -> 2240576
// aval[B*K] f32           @ 2240576  -> 2256960
// tgt[B*K] f32            @ 2256960  -> 2273344
// part4[NBLK] float4      @ 2273344  -> 2305024

__device__ inline float sl1(float x) {
    float ax = fabsf(x);
    return ax < 1.f ? 0.5f * ax * ax : ax - 1.f;
}

__global__ void init_kernel(float* accum, unsigned* cnt, float* tgt) {
    int i = blockIdx.x * 256 + threadIdx.x;
    if (i < BB * KK) tgt[i] = 0.f;
    if (i < 8) accum[i] = 0.f;
    if (i < BB) cnt[i] = 0u;
}

__global__ __launch_bounds__(256) void assign_kernel(
    const float* __restrict__ cls, const float* __restrict__ prob,
    const float* __restrict__ bbox2d, const float* __restrict__ bbox3d,
    const float* __restrict__ rois, const float* __restrict__ gtb,
    const int* __restrict__ gtl, const float* __restrict__ gt3,
    const float* __restrict__ means, const float* __restrict__ stds,
    float* scores, float4* part4)
{
    __shared__ float s_gtb[GG * 4];
    __shared__ float s_gt3[GG * 7];
    __shared__ int s_gtl[GG];
    __shared__ float s_ms[22];   // [0..10] means, [11..21] stds
    __shared__ float4 wsum[4];
    int b = blockIdx.y;
    int tid = threadIdx.x;
    if (tid < GG * 4) s_gtb[tid] = gtb[b * GG * 4 + tid];
    if (tid < GG * 7) s_gt3[tid] = gt3[b * GG * 7 + tid];
    if (tid < GG) s_gtl[tid] = gtl[b * GG + tid];
    if (tid < 11) s_ms[tid] = means[tid];
    if (tid >= 32 && tid < 43) s_ms[11 + tid - 32] = stds[tid - 32];
    __syncthreads();

    int n = blockIdx.x * 256 + tid;   // always < NN (495*256 == NN)
    float clsv = 0.f, fgv = 0.f, l2v = 0.f, l3v = 0.f;
    {
        const float4 r = *(const float4*)(rois + (size_t)n * 4);
        float aa = fmaxf(r.z - r.x, 0.f) * fmaxf(r.w - r.y, 0.f);
        float best_iou = -1.f; int bg = 0;
        #pragma unroll 4
        for (int g = 0; g < GG; ++g) {
            float gx1 = s_gtb[g * 4 + 0], gy1 = s_gtb[g * 4 + 1];
            float gx2 = s_gtb[g * 4 + 2], gy2 = s_gtb[g * 4 + 3];
            float ab = fmaxf(gx2 - gx1, 0.f) * fmaxf(gy2 - gy1, 0.f);
            float w = fmaxf(fminf(r.z, gx2) - fmaxf(r.x, gx1), 0.f);
            float h = fmaxf(fminf(r.w, gy2) - fmaxf(r.y, gy1), 0.f);
            float inter = w * h;
            float iou = inter / (aa + ab - inter + EPSf);
            if (iou > best_iou) { best_iou = iou; bg = g; }
        }
        bool fg = (best_iou >= FG_TH);

        // ---- cls loss ----
        const float4 c = *(const float4*)(cls + ((size_t)b * NN + n) * 4);
        float m = fmaxf(fmaxf(c.x, c.y), fmaxf(c.z, c.w));
        float lse = m + logf(expf(c.x - m) + expf(c.y - m) + expf(c.z - m) + expf(c.w - m));
        int label = fg ? s_gtl[bg] : 0;
        float csel = (label == 0) ? c.x : (label == 1) ? c.y : (label == 2) ? c.z : c.w;
        clsv = lse - csel;

        if (fg) {
            fgv = 1.f;
            float aw = r.z - r.x, ah = r.w - r.y;
            float acx = r.x + 0.5f * aw, acy = r.y + 0.5f * ah;
            float gx1 = s_gtb[bg * 4 + 0], gy1 = s_gtb[bg * 4 + 1];
            float gx2 = s_gtb[bg * 4 + 2], gy2 = s_gtb[bg * 4 + 3];
            float gw = gx2 - gx1, gh = gy2 - gy1;
            float gcx = gx1 + 0.5f * gw, gcy = gy1 + 0.5f * gh;
            float t0 = (gcx - acx) / (aw + EPSf);
            float t1 = (gcy - acy) / (ah + EPSf);
            float t2 = logf(gw / (aw + EPSf) + EPSf);
            float t3 = logf(gh / (ah + EPSf) + EPSf);
            t0 = (t0 - s_ms[0]) / s_ms[11];
            t1 = (t1 - s_ms[1]) / s_ms[12];
            t2 = (t2 - s_ms[2]) / s_ms[13];
            t3 = (t3 - s_ms[3]) / s_ms[14];
            const float4 d = *(const float4*)(bbox2d + ((size_t)b * NN + n) * 4);
            l2v = sl1(d.x - t0) + sl1(d.y - t1) + sl1(d.z - t2) + sl1(d.w - t3);
            const float* b3 = bbox3d + ((size_t)b * NN + n) * 7;
            for (int i = 0; i < 7; ++i) {
                float t = (s_gt3[bg * 7 + i] - s_ms[4 + i]) / s_ms[15 + i];
                l3v += sl1(b3[i] - t);
            }
        }

        // ---- NMS score ----
        const float4 p = *(const float4*)(prob + ((size_t)b * NN + n) * 4);
        scores[(size_t)b * NN + n] = fmaxf(fmaxf(p.y, p.z), p.w);
    }
    // wave reduce -> LDS -> one float4 per block (no hot atomics)
    for (int o = 32; o; o >>= 1) {
        clsv += __shfl_down(clsv, o);
        fgv  += __shfl_down(fgv, o);
        l2v  += __shfl_down(l2v, o);
        l3v  += __shfl_down(l3v, o);
    }
    int wave = tid >> 6, lane = tid & 63;
    if (lane == 0) wsum[wave] = make_float4(clsv, fgv, l2v, l3v);
    __syncthreads();
    if (tid == 0) {
        float4 s = wsum[0];
        s.x += wsum[1].x + wsum[2].x + wsum[3].x;
        s.y += wsum[1].y + wsum[2].y + wsum[3].y;
        s.z += wsum[1].z + wsum[2].z + wsum[3].z;
        s.w += wsum[1].w + wsum[2].w + wsum[3].w;
        part4[blockIdx.y * NBLKX + blockIdx.x] = s;
    }
}

__global__ __launch_bounds__(1024) void reduce_partials_kernel(
    const float4* __restrict__ part4, float* accum)
{
    __shared__ float4 ws_[16];
    int t = threadIdx.x;
    float c = 0.f, f = 0.f, l2 = 0.f, l3 = 0.f;
    for (int i = t; i < NBLK; i += 1024) {
        float4 p = part4[i];
        c += p.x; f += p.y; l2 += p.z; l3 += p.w;
    }
    for (int o = 32; o; o >>= 1) {
        c += __shfl_down(c, o); f += __shfl_down(f, o);
        l2 += __shfl_down(l2, o); l3 += __shfl_down(l3, o);
    }
    int wave = t >> 6, lane = t & 63;
    if (lane == 0) ws_[wave] = make_float4(c, f, l2, l3);
    __syncthreads();
    if (t == 0) {
        float4 s = make_float4(0.f, 0.f, 0.f, 0.f);
        for (int w = 0; w < 16; ++w) {
            s.x += ws_[w].x; s.y += ws_[w].y; s.z += ws_[w].z; s.w += ws_[w].w;
        }
        accum[0] = s.x; accum[1] = s.y; accum[2] = s.z; accum[3] = s.w;
    }
}

// one block per batch: LDS histogram + suffix scan -> threshold bin
__global__ __launch_bounds__(1024) void hist_thresh_kernel(
    const float* __restrict__ scores, unsigned* Tbin)
{
    __shared__ unsigned hist[NBIN];   // 64 KB
    int b = blockIdx.x, t = threadIdx.x;
    for (int i = t; i < NBIN; i += 1024) hist[i] = 0u;
    __syncthreads();
    for (int n = t; n < NN; n += 1024) {
        unsigned bin = __float_as_uint(scores[(size_t)b * NN + n]) >> 16;
        if (bin >= NBIN) bin = NBIN - 1;
        atomicAdd(&hist[bin], 1u);
    }
    __syncthreads();
    // save 16 fine bins to registers, coarse suffix-scan in place
    unsigned fine[16]; unsigned s = 0;
    #pragma unroll
    for (int i = 0; i < 16; ++i) { fine[i] = hist[t * 16 + i]; s += fine[i]; }
    __syncthreads();
    hist[t] = s;
    __syncthreads();
    for (int off = 1; off < 1024; off <<= 1) {
        unsigned v = hist[t] + ((t + off < 1024) ? hist[t + off] : 0u);
        __syncthreads();
        hist[t] = v;
        __syncthreads();
    }
    unsigned nxt = (t == 1023) ? 0u : hist[t + 1];
    if (hist[t] >= KK && nxt < KK) {
        unsigned cum = nxt;
        unsigned T = (unsigned)(t * 16);
        #pragma unroll
        for (int i = 15; i >= 0; --i) {
            cum += fine[i];
            if (cum >= KK) { T = (unsigned)(t * 16 + i); break; }
        }
        Tbin[b] = T;
    }
}

__global__ __launch_bounds__(256) void collect_kernel(
    const float* __restrict__ scores, const unsigned* __restrict__ Tbin,
    unsigned* cnt, unsigned long long* cand)
{
    __shared__ unsigned wc[4];
    __shared__ unsigned wbase[4];
    int b = blockIdx.y;
    int n = blockIdx.x * 256 + threadIdx.x;
    int wave = threadIdx.x >> 6, lane = threadIdx.x & 63;
    unsigned bits = __float_as_uint(scores[(size_t)b * NN + n]);
    bool pred = ((bits >> 16) >= Tbin[b]);
    unsigned long long mask = __ballot(pred);
    if (lane == 0) wc[wave] = (unsigned)__popcll(mask);
    __syncthreads();
    if (threadIdx.x == 0) {
        unsigned tot = wc[0] + wc[1] + wc[2] + wc[3];
        unsigned base = tot ? atomicAdd(&cnt[b], tot) : 0u;
        for (int w = 0; w < 4; ++w) { wbase[w] = base; base += wc[w]; }
    }
    __syncthreads();
    if (pred) {
        unsigned pos = wbase[wave] + (unsigned)__popcll(mask & ((1ull << lane) - 1ull));
        if (pos < CANDMAX)
            cand[b * CANDMAX + pos] = ((unsigned long long)bits << 32) | (unsigned)(~(unsigned)n);
    }
}

__global__ __launch_bounds__(1024) void sort_decode_kernel(
    const unsigned long long* __restrict__ cand, const unsigned* __restrict__ cnt,
    const float* __restrict__ bbox2d, const float* __restrict__ rois,
    const float* __restrict__ means, const float* __restrict__ stds,
    float* sk, float4* pred)
{
    __shared__ unsigned long long keys[CANDMAX];
    int b = blockIdx.x, t = threadIdx.x;
    unsigned c = cnt[b]; if (c > CANDMAX) c = CANDMAX;
    unsigned L = 1024; while (L < c) L <<= 1;
    for (unsigned i = t; i < L; i += 1024) keys[i] = (i < c) ? cand[b * CANDMAX + i] : 0ull;
    for (unsigned k = 2; k <= L; k <<= 1) {
        for (unsigned j = k >> 1; j > 0; j >>= 1) {
            __syncthreads();
            for (unsigned i = t; i < L; i += 1024) {
                unsigned ixj = i ^ j;
                if (ixj > i) {
                    unsigned long long a = keys[i], bb2 = keys[ixj];
                    bool up = ((i & k) == 0);
                    if (up ? (a < bb2) : (a > bb2)) { keys[i] = bb2; keys[ixj] = a; }
                }
            }
        }
    }
    __syncthreads();
    if (t < KK) {
        unsigned long long key = keys[t];
        float sc = __uint_as_float((unsigned)(key >> 32));
        unsigned n = ~((unsigned)key);
        if (n >= NN) n = NN - 1;
        const float4 d = *(const float4*)(bbox2d + ((size_t)b * NN + n) * 4);
        const float4 r = *(const float4*)(rois + (size_t)n * 4);
        float d0 = d.x * stds[0] + means[0];
        float d1 = d.y * stds[1] + means[1];
        float d2 = d.z * stds[2] + means[2];
        float d3 = d.w * stds[3] + means[3];
        float aw = r.z - r.x, ah = r.w - r.y;
        float pcx = r.x + 0.5f * aw + d0 * aw;
        float pcy = r.y + 0.5f * ah + d1 * ah;
        float pw = aw * expf(fminf(fmaxf(d2, -4.f), 4.f));
        float ph = ah * expf(fminf(fmaxf(d3, -4.f), 4.f));
        pred[b * KK + t] = make_float4(pcx - 0.5f * pw, pcy - 0.5f * ph,
                                       pcx + 0.5f * pw, pcy + 0.5f * ph);
        sk[b * KK + t] = sc;
    }
}

__global__ __launch_bounds__(1024) void solve_kernel(
    const float4* __restrict__ pred, const float* __restrict__ sk, float* aval)
{
    __shared__ float4 bx[KK];
    __shared__ float ar[KK];
    __shared__ float a_sh[KK];
    __shared__ float ldiag[64 * 65];
    int b = blockIdx.x, t = threadIdx.x;
    int wave = t >> 6, lane = t & 63;
    float4 box = pred[b * KK + t];
    float sv = sk[b * KK + t];
    float myar = fmaxf(box.z - box.x, 0.f) * fmaxf(box.w - box.y, 0.f);
    bx[t] = box;
    ar[t] = myar;
    __syncthreads();
    float partial = 0.f;
    for (int blk = 0; blk < 16; ++blk) {
        int base = blk << 6;
        // parallel precompute of diag-block L entries (strict lower, thresholded)
        for (int q = 0; q < 4; ++q) {
            int e = t + (q << 10);
            int i = e >> 6, j = e & 63;
            float v = 0.f;
            if (i > j) {
                float4 aB = bx[base + i], bB = bx[base + j];
                float w = fmaxf(fminf(aB.z, bB.z) - fmaxf(aB.x, bB.x), 0.f);
                float h = fmaxf(fminf(aB.w, bB.w) - fmaxf(aB.y, bB.y), 0.f);
                float inter = w * h;
                float iou = inter / (ar[base + i] + ar[base + j] - inter + EPSf);
                v = (iou > NMS_TH) ? iou : 0.f;
            }
            ldiag[i * 65 + j] = v;
        }
        __syncthreads();
        if (wave == blk) {
            for (int jl = 0; jl < 64; ++jl) {
                float av = sv - partial;
                float aj = __shfl(av, jl);
                partial += ldiag[lane * 65 + jl] * aj;   // zero for lane<=jl
            }
            a_sh[base + lane] = sv - partial;
        }
        __syncthreads();
        if (wave > blk) {
            #pragma unroll 4
            for (int jl = 0; jl < 64; ++jl) {
                int j = base + jl;
                float4 bj = bx[j];
                float w = fmaxf(fminf(box.z, bj.z) - fmaxf(box.x, bj.x), 0.f);
                float h = fmaxf(fminf(box.w, bj.w) - fmaxf(box.y, bj.y), 0.f);
                float inter = w * h;
                float iou = inter / (myar + ar[j] - inter + EPSf);
                partial += (iou > NMS_TH) ? iou * a_sh[j] : 0.f;
            }
        }
    }
    float a = sv - partial;
    aval[b * KK + t] = fminf(fmaxf(a, 0.f), 1.f);
}

__global__ __launch_bounds__(256) void best_kernel(
    const float4* __restrict__ pred, const float* __restrict__ gtb, float* tgt)
{
    int wid = blockIdx.x * 4 + (threadIdx.x >> 6);
    int lane = threadIdx.x & 63;
    int b = wid / GG, g = wid % GG;
    const float* gp = gtb + (b * GG + g) * 4;
    float gx1 = gp[0], gy1 = gp[1], gx2 = gp[2], gy2 = gp[3];
    float ab = fmaxf(gx2 - gx1, 0.f) * fmaxf(gy2 - gy1, 0.f);
    float bi = -1.f; int bk = 0;
    for (int k = lane; k < KK; k += 64) {
        float4 p = pred[b * KK + k];
        float aa = fmaxf(p.z - p.x, 0.f) * fmaxf(p.w - p.y, 0.f);
        float w = fmaxf(fminf(p.z, gx2) - fmaxf(p.x, gx1), 0.f);
        float h = fmaxf(fminf(p.w, gy2) - fmaxf(p.y, gy1), 0.f);
        float inter = w * h;
        float iou = inter / (aa + ab - inter + EPSf);
        if (iou > bi) { bi = iou; bk = k; }   // strictly greater: first-max kept
    }
    for (int o = 32; o; o >>= 1) {
        float oi = __shfl_down(bi, o);
        int ok = __shfl_down(bk, o);
        if (oi > bi || (oi == bi && ok < bk)) { bi = oi; bk = ok; }
    }
    if (lane == 0) tgt[b * KK + bk] = 1.f;
}

__global__ __launch_bounds__(1024) void bce_kernel(
    const float* __restrict__ aval, const float* __restrict__ tgt, float* accum)
{
    __shared__ float bsum[16];
    int i = blockIdx.x * 1024 + threadIdx.x;
    float v = 0.f;
    {
        float a = aval[i], tg = tgt[i];
        v = -(tg * logf(a + EPSf) + (1.f - tg) * logf(1.f - a + EPSf));
    }
    for (int o = 32; o; o >>= 1) v += __shfl_down(v, o);
    int wave = threadIdx.x >> 6, lane = threadIdx.x & 63;
    if (lane == 0) bsum[wave] = v;
    __syncthreads();
    if (threadIdx.x == 0) {
        float s = 0.f;
        for (int w = 0; w < 16; ++w) s += bsum[w];
        atomicAdd(&accum[4], s);
    }
}

__global__ void finalize_kernel(const float* __restrict__ accum, float* out) {
    if (threadIdx.x == 0 && blockIdx.x == 0) {
        float nfg = fmaxf(accum[1], 1.f);
        out[0] = accum[0] / (float)(BB * NN)
               + accum[2] / nfg
               + accum[3] / nfg
               + accum[4] / (float)(BB * KK);
    }
}

extern "C" void kernel_launch(void* const* d_in, const int* in_sizes, int n_in,
                              void* d_out, int out_size, void* d_ws, size_t ws_size,
                              hipStream_t stream) {
    const float* cls    = (const float*)d_in[0];
    const float* prob   = (const float*)d_in[1];
    const float* bbox2d = (const float*)d_in[2];
    const float* bbox3d = (const float*)d_in[3];
    const float* rois   = (const float*)d_in[4];
    const float* gtb    = (const float*)d_in[5];
    const int*   gtl    = (const int*)d_in[6];
    const float* gt3    = (const float*)d_in[7];
    const float* means  = (const float*)d_in[8];
    const float* stds   = (const float*)d_in[9];
    float* out = (float*)d_out;
    char* ws = (char*)d_ws;

    float*              accum  = (float*)(ws + 0);
    unsigned*           cnt    = (unsigned*)(ws + 32);
    unsigned*           Tbin   = (unsigned*)(ws + 48);
    unsigned long long* cand   = (unsigned long long*)(ws + 64);
    float*              scores = (float*)(ws + 131136);
    float*              sk     = (float*)(ws + 2158656);
    float4*             pred   = (float4*)(ws + 2175040);
    float*              aval   = (float*)(ws + 2240576);
    float*              tgt    = (float*)(ws + 2256960);
    float4*             part4  = (float4*)(ws + 2273344);

    init_kernel<<<dim3(16), dim3(256), 0, stream>>>(accum, cnt, tgt);

    dim3 gBN(NBLKX, BB);
    assign_kernel<<<gBN, dim3(256), 0, stream>>>(cls, prob, bbox2d, bbox3d, rois,
                                                 gtb, gtl, gt3, means, stds,
                                                 scores, part4);
    reduce_partials_kernel<<<dim3(1), dim3(1024), 0, stream>>>(part4, accum);
    hist_thresh_kernel<<<dim3(BB), dim3(1024), 0, stream>>>(scores, Tbin);
    collect_kernel<<<gBN, dim3(256), 0, stream>>>(scores, Tbin, cnt, cand);
    sort_decode_kernel<<<dim3(BB), dim3(1024), 0, stream>>>(cand, cnt, bbox2d, rois,
                                                            means, stds, sk, pred);
    solve_kernel<<<dim3(BB), dim3(1024), 0, stream>>>(pred, sk, aval);
    best_kernel<<<dim3((BB * GG) / 4), dim3(256), 0, stream>>>(pred, gtb, tgt);
    bce_kernel<<<dim3((BB * KK) / 1024), dim3(1024), 0, stream>>>(aval, tgt, accum);
    finalize_kernel<<<dim3(1), dim3(64), 0, stream>>>(accum, out);
}

// Round 3
// 277.399 us; speedup vs baseline: 2.5699x; 1.2266x over previous
//
#include <hip/hip_runtime.h>
#include <hip/hip_bf16.h>
#include <math.h>

#define BB 4
#define NN 126720
#define GG 32
#define CC 4
#define KK 1024
#define NBIN 16384
#define CANDMAX 4096
#define NBLKX 495            // NN / 256 exactly
#define NBLK (NBLKX * BB)    // 1980
#define FG_TH 0.5f
#define NMS_TH 0.4f
#define EPSf 1e-6f

// ---- ws layout (bytes) ----
// accum f32[8]        @ 0
// cnt u32[4]          @ 32
// Tbin u32[4]         @ 48
// win i32[128]        @ 64      -> 576
// cand u64[4*4096]    @ 576     -> 131648
// scores f32[B*N]     @ 131648  -> 2159168   (minvT f32[64*64*64] overlays @131648, used after scores dead)
// sk f32[B*K]         @ 2159168 -> 2175552
// pred float4[B*K]    @ 2175552 -> 2241088
// aval f32[B*K]       @ 2241088 -> 2257472
// part4 float4[NBLK]  @ 2257472 -> 2289152

__device__ inline float sl1(float x) {
    float ax = fabsf(x);
    return ax < 1.f ? 0.5f * ax * ax : ax - 1.f;
}

__global__ __launch_bounds__(256) void assign_kernel(
    const float* __restrict__ cls, const float* __restrict__ prob,
    const float* __restrict__ bbox2d, const float* __restrict__ bbox3d,
    const float* __restrict__ rois, const float* __restrict__ gtb,
    const int* __restrict__ gtl, const float* __restrict__ gt3,
    const float* __restrict__ means, const float* __restrict__ stds,
    float* scores, float4* part4)
{
    __shared__ float s_gtb[GG * 4];
    __shared__ float s_gt3[GG * 7];
    __shared__ int s_gtl[GG];
    __shared__ float s_ms[22];   // [0..10] means, [11..21] stds
    __shared__ float4 wsum[4];
    int b = blockIdx.y;
    int tid = threadIdx.x;
    if (tid < GG * 4) s_gtb[tid] = gtb[b * GG * 4 + tid];
    if (tid < GG * 7) s_gt3[tid] = gt3[b * GG * 7 + tid];
    if (tid < GG) s_gtl[tid] = gtl[b * GG + tid];
    if (tid < 11) s_ms[tid] = means[tid];
    if (tid >= 32 && tid < 43) s_ms[11 + tid - 32] = stds[tid - 32];
    __syncthreads();

    int n = blockIdx.x * 256 + tid;   // always < NN (495*256 == NN)
    float clsv = 0.f, fgv = 0.f, l2v = 0.f, l3v = 0.f;
    {
        const float4 r = *(const float4*)(rois + (size_t)n * 4);
        float aa = fmaxf(r.z - r.x, 0.f) * fmaxf(r.w - r.y, 0.f);
        float best_iou = -1.f; int bg = 0;
        #pragma unroll 4
        for (int g = 0; g < GG; ++g) {
            float gx1 = s_gtb[g * 4 + 0], gy1 = s_gtb[g * 4 + 1];
            float gx2 = s_gtb[g * 4 + 2], gy2 = s_gtb[g * 4 + 3];
            float ab = fmaxf(gx2 - gx1, 0.f) * fmaxf(gy2 - gy1, 0.f);
            float w = fmaxf(fminf(r.z, gx2) - fmaxf(r.x, gx1), 0.f);
            float h = fmaxf(fminf(r.w, gy2) - fmaxf(r.y, gy1), 0.f);
            float inter = w * h;
            float iou = inter / (aa + ab - inter + EPSf);
            if (iou > best_iou) { best_iou = iou; bg = g; }
        }
        bool fg = (best_iou >= FG_TH);

        const float4 c = *(const float4*)(cls + ((size_t)b * NN + n) * 4);
        float m = fmaxf(fmaxf(c.x, c.y), fmaxf(c.z, c.w));
        float lse = m + logf(expf(c.x - m) + expf(c.y - m) + expf(c.z - m) + expf(c.w - m));
        int label = fg ? s_gtl[bg] : 0;
        float csel = (label == 0) ? c.x : (label == 1) ? c.y : (label == 2) ? c.z : c.w;
        clsv = lse - csel;

        if (fg) {
            fgv = 1.f;
            float aw = r.z - r.x, ah = r.w - r.y;
            float acx = r.x + 0.5f * aw, acy = r.y + 0.5f * ah;
            float gx1 = s_gtb[bg * 4 + 0], gy1 = s_gtb[bg * 4 + 1];
            float gx2 = s_gtb[bg * 4 + 2], gy2 = s_gtb[bg * 4 + 3];
            float gw = gx2 - gx1, gh = gy2 - gy1;
            float gcx = gx1 + 0.5f * gw, gcy = gy1 + 0.5f * gh;
            float t0 = (gcx - acx) / (aw + EPSf);
            float t1 = (gcy - acy) / (ah + EPSf);
            float t2 = logf(gw / (aw + EPSf) + EPSf);
            float t3 = logf(gh / (ah + EPSf) + EPSf);
            t0 = (t0 - s_ms[0]) / s_ms[11];
            t1 = (t1 - s_ms[1]) / s_ms[12];
            t2 = (t2 - s_ms[2]) / s_ms[13];
            t3 = (t3 - s_ms[3]) / s_ms[14];
            const float4 d = *(const float4*)(bbox2d + ((size_t)b * NN + n) * 4);
            l2v = sl1(d.x - t0) + sl1(d.y - t1) + sl1(d.z - t2) + sl1(d.w - t3);
            const float* b3 = bbox3d + ((size_t)b * NN + n) * 7;
            for (int i = 0; i < 7; ++i) {
                float t = (s_gt3[bg * 7 + i] - s_ms[4 + i]) / s_ms[15 + i];
                l3v += sl1(b3[i] - t);
            }
        }

        const float4 p = *(const float4*)(prob + ((size_t)b * NN + n) * 4);
        scores[(size_t)b * NN + n] = fmaxf(fmaxf(p.y, p.z), p.w);
    }
    for (int o = 32; o; o >>= 1) {
        clsv += __shfl_down(clsv, o);
        fgv  += __shfl_down(fgv, o);
        l2v  += __shfl_down(l2v, o);
        l3v  += __shfl_down(l3v, o);
    }
    int wave = tid >> 6, lane = tid & 63;
    if (lane == 0) wsum[wave] = make_float4(clsv, fgv, l2v, l3v);
    __syncthreads();
    if (tid == 0) {
        float4 s = wsum[0];
        s.x += wsum[1].x + wsum[2].x + wsum[3].x;
        s.y += wsum[1].y + wsum[2].y + wsum[3].y;
        s.z += wsum[1].z + wsum[2].z + wsum[3].z;
        s.w += wsum[1].w + wsum[2].w + wsum[3].w;
        part4[blockIdx.y * NBLKX + blockIdx.x] = s;
    }
}

__global__ __launch_bounds__(1024) void reduce_partials_kernel(
    const float4* __restrict__ part4, float* accum)
{
    __shared__ float4 ws_[16];
    int t = threadIdx.x;
    float c = 0.f, f = 0.f, l2 = 0.f, l3 = 0.f;
    for (int i = t; i < NBLK; i += 1024) {
        float4 p = part4[i];
        c += p.x; f += p.y; l2 += p.z; l3 += p.w;
    }
    for (int o = 32; o; o >>= 1) {
        c += __shfl_down(c, o); f += __shfl_down(f, o);
        l2 += __shfl_down(l2, o); l3 += __shfl_down(l3, o);
    }
    int wave = t >> 6, lane = t & 63;
    if (lane == 0) ws_[wave] = make_float4(c, f, l2, l3);
    __syncthreads();
    if (t == 0) {
        float4 s = make_float4(0.f, 0.f, 0.f, 0.f);
        for (int w = 0; w < 16; ++w) {
            s.x += ws_[w].x; s.y += ws_[w].y; s.z += ws_[w].z; s.w += ws_[w].w;
        }
        accum[0] = s.x; accum[1] = s.y; accum[2] = s.z; accum[3] = s.w;
    }
}

// one block per batch: LDS histogram + suffix scan -> threshold bin; also zeroes cnt
__global__ __launch_bounds__(1024) void hist_thresh_kernel(
    const float* __restrict__ scores, unsigned* Tbin, unsigned* cnt)
{
    __shared__ unsigned hist[NBIN];   // 64 KB
    int b = blockIdx.x, t = threadIdx.x;
    if (t == 0) cnt[b] = 0u;
    for (int i = t; i < NBIN; i += 1024) hist[i] = 0u;
    __syncthreads();
    const float* sp = scores + (size_t)b * NN;
    int n = t;
    for (; n + 3072 < NN; n += 4096) {
        float v0 = sp[n], v1 = sp[n + 1024], v2 = sp[n + 2048], v3 = sp[n + 3072];
        atomicAdd(&hist[__float_as_uint(v0) >> 16], 1u);
        atomicAdd(&hist[__float_as_uint(v1) >> 16], 1u);
        atomicAdd(&hist[__float_as_uint(v2) >> 16], 1u);
        atomicAdd(&hist[__float_as_uint(v3) >> 16], 1u);
    }
    for (; n < NN; n += 1024) atomicAdd(&hist[__float_as_uint(sp[n]) >> 16], 1u);
    __syncthreads();
    unsigned fine[16]; unsigned s = 0;
    #pragma unroll
    for (int i = 0; i < 16; ++i) { fine[i] = hist[t * 16 + i]; s += fine[i]; }
    __syncthreads();
    hist[t] = s;
    __syncthreads();
    for (int off = 1; off < 1024; off <<= 1) {
        unsigned v = hist[t] + ((t + off < 1024) ? hist[t + off] : 0u);
        __syncthreads();
        hist[t] = v;
        __syncthreads();
    }
    unsigned nxt = (t == 1023) ? 0u : hist[t + 1];
    if (hist[t] >= KK && nxt < KK) {
        unsigned cum = nxt;
        unsigned T = (unsigned)(t * 16);
        #pragma unroll
        for (int i = 15; i >= 0; --i) {
            cum += fine[i];
            if (cum >= KK) { T = (unsigned)(t * 16 + i); break; }
        }
        Tbin[b] = T;
    }
}

__global__ __launch_bounds__(256) void collect_kernel(
    const float* __restrict__ scores, const unsigned* __restrict__ Tbin,
    unsigned* cnt, unsigned long long* cand)
{
    __shared__ unsigned wc[4];
    __shared__ unsigned wbase[4];
    int b = blockIdx.y;
    int n = blockIdx.x * 256 + threadIdx.x;
    int wave = threadIdx.x >> 6, lane = threadIdx.x & 63;
    unsigned bits = __float_as_uint(scores[(size_t)b * NN + n]);
    bool pr = ((bits >> 16) >= Tbin[b]);
    unsigned long long mask = __ballot(pr);
    if (lane == 0) wc[wave] = (unsigned)__popcll(mask);
    __syncthreads();
    if (threadIdx.x == 0) {
        unsigned tot = wc[0] + wc[1] + wc[2] + wc[3];
        unsigned base = tot ? atomicAdd(&cnt[b], tot) : 0u;
        for (int w = 0; w < 4; ++w) { wbase[w] = base; base += wc[w]; }
    }
    __syncthreads();
    if (pr) {
        unsigned pos = wbase[wave] + (unsigned)__popcll(mask & ((1ull << lane) - 1ull));
        if (pos < CANDMAX)
            cand[b * CANDMAX + pos] = ((unsigned long long)bits << 32) | (unsigned)(~(unsigned)n);
    }
}

__global__ __launch_bounds__(1024) void sort_decode_kernel(
    const unsigned long long* __restrict__ cand, const unsigned* __restrict__ cnt,
    const float* __restrict__ bbox2d, const float* __restrict__ rois,
    const float* __restrict__ means, const float* __restrict__ stds,
    float* sk, float4* pred)
{
    __shared__ unsigned long long keys[CANDMAX];
    int b = blockIdx.x, t = threadIdx.x;
    unsigned c = cnt[b]; if (c > CANDMAX) c = CANDMAX;
    unsigned L = 1024; while (L < c) L <<= 1;
    for (unsigned i = t; i < L; i += 1024) keys[i] = (i < c) ? cand[b * CANDMAX + i] : 0ull;
    for (unsigned k = 2; k <= L; k <<= 1) {
        for (unsigned j = k >> 1; j > 0; j >>= 1) {
            __syncthreads();
            for (unsigned i = t; i < L; i += 1024) {
                unsigned ixj = i ^ j;
                if (ixj > i) {
                    unsigned long long a = keys[i], bb2 = keys[ixj];
                    bool up = ((i & k) == 0);
                    if (up ? (a < bb2) : (a > bb2)) { keys[i] = bb2; keys[ixj] = a; }
                }
            }
        }
    }
    __syncthreads();
    if (t < KK) {
        unsigned long long key = keys[t];
        float sc = __uint_as_float((unsigned)(key >> 32));
        unsigned n = ~((unsigned)key);
        if (n >= NN) n = NN - 1;
        const float4 d = *(const float4*)(bbox2d + ((size_t)b * NN + n) * 4);
        const float4 r = *(const float4*)(rois + (size_t)n * 4);
        float d0 = d.x * stds[0] + means[0];
        float d1 = d.y * stds[1] + means[1];
        float d2 = d.z * stds[2] + means[2];
        float d3 = d.w * stds[3] + means[3];
        float aw = r.z - r.x, ah = r.w - r.y;
        float pcx = r.x + 0.5f * aw + d0 * aw;
        float pcy = r.y + 0.5f * ah + d1 * ah;
        float pw = aw * expf(fminf(fmaxf(d2, -4.f), 4.f));
        float ph = ah * expf(fminf(fmaxf(d3, -4.f), 4.f));
        pred[b * KK + t] = make_float4(pcx - 0.5f * pw, pcy - 0.5f * ph,
                                       pcx + 0.5f * pw, pcy + 0.5f * ph);
        sk[b * KK + t] = sc;
    }
}

// one wave per (batch, 64-block): compute (I + L_dd)^{-1}, store transposed for
// coalesced row loads in solve: minvT[(m*64 + j)*64 + i] = Minv[i][j]
__global__ __launch_bounds__(64) void minv_kernel(
    const float4* __restrict__ pred, float* __restrict__ minvT)
{
    __shared__ float4 box_sh[64];
    __shared__ float ar_sh[64];
    __shared__ float Lr[64 * 68];
    __shared__ float Xt[64 * 65];
    int mId = blockIdx.x;            // 0..63 = b*16 + blk
    int b = mId >> 4, blk = mId & 15;
    int c = threadIdx.x;             // lane / column id
    float4 bxv = pred[(size_t)b * KK + blk * 64 + c];
    float myar = fmaxf(bxv.z - bxv.x, 0.f) * fmaxf(bxv.w - bxv.y, 0.f);
    box_sh[c] = bxv;
    ar_sh[c] = myar;
    __syncthreads();
    // row c of L (strict lower, thresholded); zeros elsewhere
    for (int j = 0; j < 64; ++j) {
        float4 o = box_sh[j];
        float w = fmaxf(fminf(bxv.z, o.z) - fmaxf(bxv.x, o.x), 0.f);
        float h = fmaxf(fminf(bxv.w, o.w) - fmaxf(bxv.y, o.y), 0.f);
        float inter = w * h;
        float iou = inter / (myar + ar_sh[j] - inter + EPSf);
        Lr[c * 68 + j] = (c > j && iou > NMS_TH) ? iou : 0.f;
    }
    __syncthreads();
    // columnwise forward substitution; lane c computes column c of Minv.
    // x[] fully statically indexed (stays in VGPRs).
    float x[64];
    #pragma unroll
    for (int j = 0; j < 64; ++j) x[j] = (j == c) ? 1.f : 0.f;
    #pragma unroll
    for (int j = 1; j < 64; ++j) {
        float s0 = 0.f, s1 = 0.f, s2 = 0.f, s3 = 0.f;
        const int jm = (j + 3) & ~3;   // round up; extra cols hold zeros
        #pragma unroll
        for (int mm = 0; mm < jm; mm += 4) {
            float4 Lv = *(const float4*)&Lr[j * 68 + mm];
            s0 += Lv.x * x[mm];
            s1 += Lv.y * x[mm + 1];
            s2 += Lv.z * x[mm + 2];
            s3 += Lv.w * x[mm + 3];
        }
        x[j] -= (s0 + s1) + (s2 + s3);
    }
    // transpose via LDS (pad 65 keeps both phases conflict-light)
    #pragma unroll
    for (int j = 0; j < 64; ++j) Xt[j * 65 + c] = x[j];
    __syncthreads();
    for (int j = 0; j < 64; ++j)
        minvT[((size_t)mId * 64 + j) * 64 + c] = Xt[c * 65 + j];
}

__global__ __launch_bounds__(1024) void solve_kernel(
    const float4* __restrict__ pred, const float* __restrict__ sk,
    const float* __restrict__ minvT, float* __restrict__ aval)
{
    __shared__ float4 bx[KK];
    __shared__ float ar[KK];
    __shared__ float a_sh[KK];
    int b = blockIdx.x, t = threadIdx.x;
    int wave = t >> 6, lane = t & 63;
    float4 box = pred[(size_t)b * KK + t];
    float sv = sk[(size_t)b * KK + t];
    float myar = fmaxf(box.z - box.x, 0.f) * fmaxf(box.w - box.y, 0.f);
    bx[t] = box; ar[t] = myar;
    // preload this wave's Minv: lane holds row `lane` of matrix (b, wave)
    float mrow[64];
    {
        const float* mp = minvT + ((size_t)(b * 16 + wave) * 64) * 64 + lane;
        #pragma unroll
        for (int j = 0; j < 64; ++j) mrow[j] = mp[j * 64];
    }
    __syncthreads();
    float partial = 0.f, areg = 0.f;
    for (int blk = 0; blk < 16; ++blk) {
        int base = blk << 6;
        if (wave == blk) {
            // a_blk = Minv * (s - partial): 64 independent shfl+fma (no serial chain)
            float tval = sv - partial;
            float a0 = 0.f, a1 = 0.f, a2 = 0.f, a3 = 0.f;
            #pragma unroll
            for (int j = 0; j < 64; j += 4) {
                a0 += mrow[j]     * __shfl(tval, j);
                a1 += mrow[j + 1] * __shfl(tval, j + 1);
                a2 += mrow[j + 2] * __shfl(tval, j + 2);
                a3 += mrow[j + 3] * __shfl(tval, j + 3);
            }
            areg = (a0 + a1) + (a2 + a3);
            a_sh[base + lane] = areg;
        }
        __syncthreads();   // a_sh[base..base+63] visible
        if (wave > blk) {
            // trailing update: all LDS reads are wave-uniform broadcasts
            float p0 = 0.f, p1 = 0.f;
            #pragma unroll 8
            for (int jl = 0; jl < 64; jl += 2) {
                int j0 = base + jl, j1 = j0 + 1;
                float4 b0 = bx[j0], b1 = bx[j1];
                float w0 = fmaxf(fminf(box.z, b0.z) - fmaxf(box.x, b0.x), 0.f);
                float h0 = fmaxf(fminf(box.w, b0.w) - fmaxf(box.y, b0.y), 0.f);
                float i0 = w0 * h0;
                float u0 = i0 / (myar + ar[j0] - i0 + EPSf);
                p0 += (u0 > NMS_TH) ? u0 * a_sh[j0] : 0.f;
                float w1 = fmaxf(fminf(box.z, b1.z) - fmaxf(box.x, b1.x), 0.f);
                float h1 = fmaxf(fminf(box.w, b1.w) - fmaxf(box.y, b1.y), 0.f);
                float i1 = w1 * h1;
                float u1 = i1 / (myar + ar[j1] - i1 + EPSf);
                p1 += (u1 > NMS_TH) ? u1 * a_sh[j1] : 0.f;
            }
            partial += p0 + p1;
        }
    }
    aval[(size_t)b * KK + t] = fminf(fmaxf(areg, 0.f), 1.f);
}

__global__ __launch_bounds__(256) void best_kernel(
    const float4* __restrict__ pred, const float* __restrict__ gtb, int* win)
{
    int wid = blockIdx.x * 4 + (threadIdx.x >> 6);
    int lane = threadIdx.x & 63;
    int b = wid / GG, g = wid % GG;
    const float* gp = gtb + (b * GG + g) * 4;
    float gx1 = gp[0], gy1 = gp[1], gx2 = gp[2], gy2 = gp[3];
    float ab = fmaxf(gx2 - gx1, 0.f) * fmaxf(gy2 - gy1, 0.f);
    float bi = -1.f; int bk = 0;
    for (int k = lane; k < KK; k += 64) {
        float4 p = pred[b * KK + k];
        float aa = fmaxf(p.z - p.x, 0.f) * fmaxf(p.w - p.y, 0.f);
        float w = fmaxf(fminf(p.z, gx2) - fmaxf(p.x, gx1), 0.f);
        float h = fmaxf(fminf(p.w, gy2) - fmaxf(p.y, gy1), 0.f);
        float inter = w * h;
        float iou = inter / (aa + ab - inter + EPSf);
        if (iou > bi) { bi = iou; bk = k; }   // strict >: first max kept
    }
    for (int o = 32; o; o >>= 1) {
        float oi = __shfl_down(bi, o);
        int ok = __shfl_down(bk, o);
        if (oi > bi || (oi == bi && ok < bk)) { bi = oi; bk = ok; }
    }
    if (lane == 0) win[b * GG + g] = bk;
}

__global__ __launch_bounds__(1024) void bce_final_kernel(
    const float* __restrict__ aval, const int* __restrict__ win,
    const float* __restrict__ accum, float* __restrict__ out)
{
    __shared__ int w_sh[BB * GG];
    __shared__ float bsum[16];
    int t = threadIdx.x;
    if (t < BB * GG) w_sh[t] = win[t];
    __syncthreads();
    float v = 0.f;
    #pragma unroll
    for (int q = 0; q < 4; ++q) {
        int i = q * 1024 + t;
        int b = i >> 10, k = i & 1023;
        float tg = 0.f;
        for (int g = 0; g < GG; ++g) if (w_sh[b * GG + g] == k) tg = 1.f;
        float a = aval[i];
        v += -(tg * logf(a + EPSf) + (1.f - tg) * logf(1.f - a + EPSf));
    }
    for (int o = 32; o; o >>= 1) v += __shfl_down(v, o);
    int wv = t >> 6, ln = t & 63;
    if (ln == 0) bsum[wv] = v;
    __syncthreads();
    if (t == 0) {
        float s = 0.f;
        for (int w = 0; w < 16; ++w) s += bsum[w];
        float nfg = fmaxf(accum[1], 1.f);
        out[0] = accum[0] / (float)(BB * NN)
               + accum[2] / nfg
               + accum[3] / nfg
               + s / (float)(BB * KK);
    }
}

extern "C" void kernel_launch(void* const* d_in, const int* in_sizes, int n_in,
                              void* d_out, int out_size, void* d_ws, size_t ws_size,
                              hipStream_t stream) {
    const float* cls    = (const float*)d_in[0];
    const float* prob   = (const float*)d_in[1];
    const float* bbox2d = (const float*)d_in[2];
    const float* bbox3d = (const float*)d_in[3];
    const float* rois   = (const float*)d_in[4];
    const float* gtb    = (const float*)d_in[5];
    const int*   gtl    = (const int*)d_in[6];
    const float* gt3    = (const float*)d_in[7];
    const float* means  = (const float*)d_in[8];
    const float* stds   = (const float*)d_in[9];
    float* out = (float*)d_out;
    char* ws = (char*)d_ws;

    float*              accum  = (float*)(ws + 0);
    unsigned*           cnt    = (unsigned*)(ws + 32);
    unsigned*           Tbin   = (unsigned*)(ws + 48);
    int*                win    = (int*)(ws + 64);
    unsigned long long* cand   = (unsigned long long*)(ws + 576);
    float*              scores = (float*)(ws + 131648);
    float*              minvT  = (float*)(ws + 131648);   // overlays scores (dead after collect)
    float*              sk     = (float*)(ws + 2159168);
    float4*             pred   = (float4*)(ws + 2175552);
    float*              aval   = (float*)(ws + 2241088);
    float4*             part4  = (float4*)(ws + 2257472);

    dim3 gBN(NBLKX, BB);
    assign_kernel<<<gBN, dim3(256), 0, stream>>>(cls, prob, bbox2d, bbox3d, rois,
                                                 gtb, gtl, gt3, means, stds,
                                                 scores, part4);
    reduce_partials_kernel<<<dim3(1), dim3(1024), 0, stream>>>(part4, accum);
    hist_thresh_kernel<<<dim3(BB), dim3(1024), 0, stream>>>(scores, Tbin, cnt);
    collect_kernel<<<gBN, dim3(256), 0, stream>>>(scores, Tbin, cnt, cand);
    sort_decode_kernel<<<dim3(BB), dim3(1024), 0, stream>>>(cand, cnt, bbox2d, rois,
                                                            means, stds, sk, pred);
    minv_kernel<<<dim3(BB * 16), dim3(64), 0, stream>>>(pred, minvT);
    solve_kernel<<<dim3(BB), dim3(1024), 0, stream>>>(pred, sk, minvT, aval);
    best_kernel<<<dim3((BB * GG) / 4), dim3(256), 0, stream>>>(pred, gtb, win);
    bce_final_kernel<<<dim3(1), dim3(1024), 0, stream>>>(aval, win, accum, out);
}

// Round 4
// 153.934 us; speedup vs baseline: 4.6311x; 1.8021x over previous
//
#include <hip/hip_runtime.h>
#include <hip/hip_bf16.h>
#include <math.h>

#define BB 4
#define NN 126720
#define GG 32
#define CC 4
#define KK 1024
#define NBIN 16384
#define CANDMAX 4096
#define NBLKX 495            // NN / 256 exactly
#define NBLK (NBLKX * BB)    // 1980
#define FG_TH 0.5f
#define NMS_TH 0.4f
#define EPSf 1e-6f

// ---- ws layout (bytes) ----
// accum f32[8]        @ 0
// cnt u32[4]          @ 32
// Tbin u32[4]         @ 48
// win i32[128]        @ 64      -> 576
// cand u64[4*4096]    @ 576     -> 131648
// scores f32[B*N]     @ 131648  -> 2159168   (minvT f32[64*64*64] overlays @131648)
// sk f32[B*K]         @ 2159168 -> 2175552
// pred float4[B*K]    @ 2175552 -> 2241088
// aval f32[B*K]       @ 2241088 -> 2257472
// part4 float4[NBLK]  @ 2257472 -> 2289152
// masks u64[4*16*1024]@ 2289152 -> 2813440

__device__ inline float sl1(float x) {
    float ax = fabsf(x);
    return ax < 1.f ? 0.5f * ax * ax : ax - 1.f;
}

__global__ __launch_bounds__(256) void assign_kernel(
    const float* __restrict__ cls, const float* __restrict__ prob,
    const float* __restrict__ bbox2d, const float* __restrict__ bbox3d,
    const float* __restrict__ rois, const float* __restrict__ gtb,
    const int* __restrict__ gtl, const float* __restrict__ gt3,
    const float* __restrict__ means, const float* __restrict__ stds,
    float* scores, float4* part4)
{
    __shared__ float s_gtb[GG * 4];
    __shared__ float s_gt3[GG * 7];
    __shared__ int s_gtl[GG];
    __shared__ float s_ms[22];   // [0..10] means, [11..21] stds
    __shared__ float4 wsum[4];
    int b = blockIdx.y;
    int tid = threadIdx.x;
    if (tid < GG * 4) s_gtb[tid] = gtb[b * GG * 4 + tid];
    if (tid < GG * 7) s_gt3[tid] = gt3[b * GG * 7 + tid];
    if (tid < GG) s_gtl[tid] = gtl[b * GG + tid];
    if (tid < 11) s_ms[tid] = means[tid];
    if (tid >= 32 && tid < 43) s_ms[11 + tid - 32] = stds[tid - 32];
    __syncthreads();

    int n = blockIdx.x * 256 + tid;   // always < NN (495*256 == NN)
    float clsv = 0.f, fgv = 0.f, l2v = 0.f, l3v = 0.f;
    {
        const float4 r = *(const float4*)(rois + (size_t)n * 4);
        float aa = fmaxf(r.z - r.x, 0.f) * fmaxf(r.w - r.y, 0.f);
        float best_iou = -1.f; int bg = 0;
        #pragma unroll 4
        for (int g = 0; g < GG; ++g) {
            float gx1 = s_gtb[g * 4 + 0], gy1 = s_gtb[g * 4 + 1];
            float gx2 = s_gtb[g * 4 + 2], gy2 = s_gtb[g * 4 + 3];
            float ab = fmaxf(gx2 - gx1, 0.f) * fmaxf(gy2 - gy1, 0.f);
            float w = fmaxf(fminf(r.z, gx2) - fmaxf(r.x, gx1), 0.f);
            float h = fmaxf(fminf(r.w, gy2) - fmaxf(r.y, gy1), 0.f);
            float inter = w * h;
            float iou = inter / (aa + ab - inter + EPSf);
            if (iou > best_iou) { best_iou = iou; bg = g; }
        }
        bool fg = (best_iou >= FG_TH);

        const float4 c = *(const float4*)(cls + ((size_t)b * NN + n) * 4);
        float m = fmaxf(fmaxf(c.x, c.y), fmaxf(c.z, c.w));
        float lse = m + logf(expf(c.x - m) + expf(c.y - m) + expf(c.z - m) + expf(c.w - m));
        int label = fg ? s_gtl[bg] : 0;
        float csel = (label == 0) ? c.x : (label == 1) ? c.y : (label == 2) ? c.z : c.w;
        clsv = lse - csel;

        if (fg) {
            fgv = 1.f;
            float aw = r.z - r.x, ah = r.w - r.y;
            float acx = r.x + 0.5f * aw, acy = r.y + 0.5f * ah;
            float gx1 = s_gtb[bg * 4 + 0], gy1 = s_gtb[bg * 4 + 1];
            float gx2 = s_gtb[bg * 4 + 2], gy2 = s_gtb[bg * 4 + 3];
            float gw = gx2 - gx1, gh = gy2 - gy1;
            float gcx = gx1 + 0.5f * gw, gcy = gy1 + 0.5f * gh;
            float t0 = (gcx - acx) / (aw + EPSf);
            float t1 = (gcy - acy) / (ah + EPSf);
            float t2 = logf(gw / (aw + EPSf) + EPSf);
            float t3 = logf(gh / (ah + EPSf) + EPSf);
            t0 = (t0 - s_ms[0]) / s_ms[11];
            t1 = (t1 - s_ms[1]) / s_ms[12];
            t2 = (t2 - s_ms[2]) / s_ms[13];
            t3 = (t3 - s_ms[3]) / s_ms[14];
            const float4 d = *(const float4*)(bbox2d + ((size_t)b * NN + n) * 4);
            l2v = sl1(d.x - t0) + sl1(d.y - t1) + sl1(d.z - t2) + sl1(d.w - t3);
            const float* b3 = bbox3d + ((size_t)b * NN + n) * 7;
            for (int i = 0; i < 7; ++i) {
                float t = (s_gt3[bg * 7 + i] - s_ms[4 + i]) / s_ms[15 + i];
                l3v += sl1(b3[i] - t);
            }
        }

        const float4 p = *(const float4*)(prob + ((size_t)b * NN + n) * 4);
        scores[(size_t)b * NN + n] = fmaxf(fmaxf(p.y, p.z), p.w);
    }
    for (int o = 32; o; o >>= 1) {
        clsv += __shfl_down(clsv, o);
        fgv  += __shfl_down(fgv, o);
        l2v  += __shfl_down(l2v, o);
        l3v  += __shfl_down(l3v, o);
    }
    int wave = tid >> 6, lane = tid & 63;
    if (lane == 0) wsum[wave] = make_float4(clsv, fgv, l2v, l3v);
    __syncthreads();
    if (tid == 0) {
        float4 s = wsum[0];
        s.x += wsum[1].x + wsum[2].x + wsum[3].x;
        s.y += wsum[1].y + wsum[2].y + wsum[3].y;
        s.z += wsum[1].z + wsum[2].z + wsum[3].z;
        s.w += wsum[1].w + wsum[2].w + wsum[3].w;
        part4[blockIdx.y * NBLKX + blockIdx.x] = s;
    }
}

__global__ __launch_bounds__(1024) void reduce_partials_kernel(
    const float4* __restrict__ part4, float* accum)
{
    __shared__ float4 ws_[16];
    int t = threadIdx.x;
    float c = 0.f, f = 0.f, l2 = 0.f, l3 = 0.f;
    for (int i = t; i < NBLK; i += 1024) {
        float4 p = part4[i];
        c += p.x; f += p.y; l2 += p.z; l3 += p.w;
    }
    for (int o = 32; o; o >>= 1) {
        c += __shfl_down(c, o); f += __shfl_down(f, o);
        l2 += __shfl_down(l2, o); l3 += __shfl_down(l3, o);
    }
    int wave = t >> 6, lane = t & 63;
    if (lane == 0) ws_[wave] = make_float4(c, f, l2, l3);
    __syncthreads();
    if (t == 0) {
        float4 s = make_float4(0.f, 0.f, 0.f, 0.f);
        for (int w = 0; w < 16; ++w) {
            s.x += ws_[w].x; s.y += ws_[w].y; s.z += ws_[w].z; s.w += ws_[w].w;
        }
        accum[0] = s.x; accum[1] = s.y; accum[2] = s.z; accum[3] = s.w;
    }
}

// one block per batch: LDS histogram + suffix scan -> threshold bin; also zeroes cnt
__global__ __launch_bounds__(1024) void hist_thresh_kernel(
    const float* __restrict__ scores, unsigned* Tbin, unsigned* cnt)
{
    __shared__ unsigned hist[NBIN];   // 64 KB
    int b = blockIdx.x, t = threadIdx.x;
    if (t == 0) cnt[b] = 0u;
    for (int i = t; i < NBIN; i += 1024) hist[i] = 0u;
    __syncthreads();
    const float* sp = scores + (size_t)b * NN;
    int n = t;
    for (; n + 3072 < NN; n += 4096) {
        float v0 = sp[n], v1 = sp[n + 1024], v2 = sp[n + 2048], v3 = sp[n + 3072];
        atomicAdd(&hist[__float_as_uint(v0) >> 16], 1u);
        atomicAdd(&hist[__float_as_uint(v1) >> 16], 1u);
        atomicAdd(&hist[__float_as_uint(v2) >> 16], 1u);
        atomicAdd(&hist[__float_as_uint(v3) >> 16], 1u);
    }
    for (; n < NN; n += 1024) atomicAdd(&hist[__float_as_uint(sp[n]) >> 16], 1u);
    __syncthreads();
    unsigned fine[16]; unsigned s = 0;
    #pragma unroll
    for (int i = 0; i < 16; ++i) { fine[i] = hist[t * 16 + i]; s += fine[i]; }
    __syncthreads();
    hist[t] = s;
    __syncthreads();
    for (int off = 1; off < 1024; off <<= 1) {
        unsigned v = hist[t] + ((t + off < 1024) ? hist[t + off] : 0u);
        __syncthreads();
        hist[t] = v;
        __syncthreads();
    }
    unsigned nxt = (t == 1023) ? 0u : hist[t + 1];
    if (hist[t] >= KK && nxt < KK) {
        unsigned cum = nxt;
        unsigned T = (unsigned)(t * 16);
        #pragma unroll
        for (int i = 15; i >= 0; --i) {
            cum += fine[i];
            if (cum >= KK) { T = (unsigned)(t * 16 + i); break; }
        }
        Tbin[b] = T;
    }
}

__global__ __launch_bounds__(256) void collect_kernel(
    const float* __restrict__ scores, const unsigned* __restrict__ Tbin,
    unsigned* cnt, unsigned long long* cand)
{
    __shared__ unsigned wc[4];
    __shared__ unsigned wbase[4];
    int b = blockIdx.y;
    int n = blockIdx.x * 256 + threadIdx.x;
    int wave = threadIdx.x >> 6, lane = threadIdx.x & 63;
    unsigned bits = __float_as_uint(scores[(size_t)b * NN + n]);
    bool pr = ((bits >> 16) >= Tbin[b]);
    unsigned long long mask = __ballot(pr);
    if (lane == 0) wc[wave] = (unsigned)__popcll(mask);
    __syncthreads();
    if (threadIdx.x == 0) {
        unsigned tot = wc[0] + wc[1] + wc[2] + wc[3];
        unsigned base = tot ? atomicAdd(&cnt[b], tot) : 0u;
        for (int w = 0; w < 4; ++w) { wbase[w] = base; base += wc[w]; }
    }
    __syncthreads();
    if (pr) {
        unsigned pos = wbase[wave] + (unsigned)__popcll(mask & ((1ull << lane) - 1ull));
        if (pos < CANDMAX)
            cand[b * CANDMAX + pos] = ((unsigned long long)bits << 32) | (unsigned)(~(unsigned)n);
    }
}

__global__ __launch_bounds__(1024) void sort_decode_kernel(
    const unsigned long long* __restrict__ cand, const unsigned* __restrict__ cnt,
    const float* __restrict__ bbox2d, const float* __restrict__ rois,
    const float* __restrict__ means, const float* __restrict__ stds,
    float* sk, float4* pred)
{
    __shared__ unsigned long long keys[CANDMAX];
    int b = blockIdx.x, t = threadIdx.x;
    unsigned c = cnt[b]; if (c > CANDMAX) c = CANDMAX;
    unsigned L = 1024; while (L < c) L <<= 1;
    for (unsigned i = t; i < L; i += 1024) keys[i] = (i < c) ? cand[b * CANDMAX + i] : 0ull;
    for (unsigned k = 2; k <= L; k <<= 1) {
        for (unsigned j = k >> 1; j > 0; j >>= 1) {
            __syncthreads();
            for (unsigned i = t; i < L; i += 1024) {
                unsigned ixj = i ^ j;
                if (ixj > i) {
                    unsigned long long a = keys[i], bb2 = keys[ixj];
                    bool up = ((i & k) == 0);
                    if (up ? (a < bb2) : (a > bb2)) { keys[i] = bb2; keys[ixj] = a; }
                }
            }
        }
    }
    __syncthreads();
    if (t < KK) {
        unsigned long long key = keys[t];
        float sc = __uint_as_float((unsigned)(key >> 32));
        unsigned n = ~((unsigned)key);
        if (n >= NN) n = NN - 1;
        const float4 d = *(const float4*)(bbox2d + ((size_t)b * NN + n) * 4);
        const float4 r = *(const float4*)(rois + (size_t)n * 4);
        float d0 = d.x * stds[0] + means[0];
        float d1 = d.y * stds[1] + means[1];
        float d2 = d.z * stds[2] + means[2];
        float d3 = d.w * stds[3] + means[3];
        float aw = r.z - r.x, ah = r.w - r.y;
        float pcx = r.x + 0.5f * aw + d0 * aw;
        float pcy = r.y + 0.5f * ah + d1 * ah;
        float pw = aw * expf(fminf(fmaxf(d2, -4.f), 4.f));
        float ph = ah * expf(fminf(fmaxf(d3, -4.f), 4.f));
        pred[b * KK + t] = make_float4(pcx - 0.5f * pw, pcy - 0.5f * ph,
                                       pcx + 0.5f * pw, pcy + 0.5f * ph);
        sk[b * KK + t] = sc;
    }
}

// one wave per (batch, 64-block): compute (I + L_dd)^{-1}, store transposed for
// coalesced row loads in solve: minvT[(m*64 + j)*64 + i] = Minv[i][j]
__global__ __launch_bounds__(64) void minv_kernel(
    const float4* __restrict__ pred, float* __restrict__ minvT)
{
    __shared__ float4 box_sh[64];
    __shared__ float ar_sh[64];
    __shared__ float Lr[64 * 68];
    __shared__ float Xt[64 * 65];
    int mId = blockIdx.x;            // 0..63 = b*16 + blk
    int b = mId >> 4, blk = mId & 15;
    int c = threadIdx.x;             // lane / column id
    float4 bxv = pred[(size_t)b * KK + blk * 64 + c];
    float myar = fmaxf(bxv.z - bxv.x, 0.f) * fmaxf(bxv.w - bxv.y, 0.f);
    box_sh[c] = bxv;
    ar_sh[c] = myar;
    __syncthreads();
    for (int j = 0; j < 64; ++j) {
        float4 o = box_sh[j];
        float w = fmaxf(fminf(bxv.z, o.z) - fmaxf(bxv.x, o.x), 0.f);
        float h = fmaxf(fminf(bxv.w, o.w) - fmaxf(bxv.y, o.y), 0.f);
        float inter = w * h;
        float iou = inter / (myar + ar_sh[j] - inter + EPSf);
        Lr[c * 68 + j] = (c > j && iou > NMS_TH) ? iou : 0.f;
    }
    __syncthreads();
    float x[64];
    #pragma unroll
    for (int j = 0; j < 64; ++j) x[j] = (j == c) ? 1.f : 0.f;
    #pragma unroll
    for (int j = 1; j < 64; ++j) {
        float s0 = 0.f, s1 = 0.f, s2 = 0.f, s3 = 0.f;
        const int jm = (j + 3) & ~3;
        #pragma unroll
        for (int mm = 0; mm < jm; mm += 4) {
            float4 Lv = *(const float4*)&Lr[j * 68 + mm];
            s0 += Lv.x * x[mm];
            s1 += Lv.y * x[mm + 1];
            s2 += Lv.z * x[mm + 2];
            s3 += Lv.w * x[mm + 3];
        }
        x[j] -= (s0 + s1) + (s2 + s3);
    }
    #pragma unroll
    for (int j = 0; j < 64; ++j) Xt[j * 65 + c] = x[j];
    __syncthreads();
    for (int j = 0; j < 64; ++j)
        minvT[((size_t)mId * 64 + j) * 64 + c] = Xt[c * 65 + j];
}

// sparsity pattern of L: masks[(b*16 + cblock)*1024 + row] bit j =
//   (cblock*64+j < row) && IoU(pred[row], pred[cblock*64+j]) > NMS_TH
__global__ __launch_bounds__(256) void pmask_kernel(
    const float4* __restrict__ pred, unsigned long long* __restrict__ masks)
{
    __shared__ float4 rbox[64];
    __shared__ float rar[64];
    int cb = blockIdx.x, rb = blockIdx.y, b = blockIdx.z;
    int t = threadIdx.x, wave = t >> 6, lane = t & 63;
    if (t < 64) {
        float4 rv = pred[(size_t)b * KK + rb * 64 + t];
        rbox[t] = rv;
        rar[t] = fmaxf(rv.z - rv.x, 0.f) * fmaxf(rv.w - rv.y, 0.f);
    }
    float4 cbox = pred[(size_t)b * KK + cb * 64 + lane];
    float car = fmaxf(cbox.z - cbox.x, 0.f) * fmaxf(cbox.w - cbox.y, 0.f);
    int col = cb * 64 + lane;
    __syncthreads();
    #pragma unroll
    for (int i = 0; i < 16; ++i) {
        int rl = wave * 16 + i;
        int row = rb * 64 + rl;
        float4 rv = rbox[rl];
        float w = fmaxf(fminf(cbox.z, rv.z) - fmaxf(cbox.x, rv.x), 0.f);
        float h = fmaxf(fminf(cbox.w, rv.w) - fmaxf(cbox.y, rv.y), 0.f);
        float inter = w * h;
        float iou = inter / (car + rar[rl] - inter + EPSf);
        bool p = (col < row) && (iou > NMS_TH);
        unsigned long long m = __ballot(p);
        if (lane == 0) masks[(((size_t)b * 16 + cb) << 10) + row] = m;
    }
}

__global__ __launch_bounds__(1024) void solve_kernel(
    const float4* __restrict__ pred, const float* __restrict__ sk,
    const float* __restrict__ minvT, const unsigned long long* __restrict__ masks,
    float* __restrict__ aval)
{
    __shared__ float4 bx[KK];
    __shared__ float ar[KK];
    __shared__ float a_sh[KK];
    int b = blockIdx.x, t = threadIdx.x;
    int wave = t >> 6, lane = t & 63;
    float4 box = pred[(size_t)b * KK + t];
    float sv = sk[(size_t)b * KK + t];
    float myar = fmaxf(box.z - box.x, 0.f) * fmaxf(box.w - box.y, 0.f);
    bx[t] = box; ar[t] = myar;
    float mrow[64];
    {
        const float* mp = minvT + ((size_t)(b * 16 + wave) * 64) * 64 + lane;
        #pragma unroll
        for (int j = 0; j < 64; ++j) mrow[j] = mp[j * 64];
    }
    const unsigned long long* mbase = masks + (((size_t)b * 16) << 10) + t;
    unsigned long long mcur = mbase[0];
    __syncthreads();
    float partial = 0.f, areg = 0.f;
    for (int blk = 0; blk < 16; ++blk) {
        if (wave == blk) {
            // a_blk = Minv * (s - partial): 64 independent shfl+fma
            float tval = sv - partial;
            float a0 = 0.f, a1 = 0.f, a2 = 0.f, a3 = 0.f;
            #pragma unroll
            for (int j = 0; j < 64; j += 4) {
                a0 += mrow[j]     * __shfl(tval, j);
                a1 += mrow[j + 1] * __shfl(tval, j + 1);
                a2 += mrow[j + 2] * __shfl(tval, j + 2);
                a3 += mrow[j + 3] * __shfl(tval, j + 3);
            }
            areg = (a0 + a1) + (a2 + a3);
            a_sh[(blk << 6) + lane] = areg;
        }
        unsigned long long mnext = (blk < 15) ? mbase[(size_t)(blk + 1) << 10] : 0ull;
        __syncthreads();   // a_sh[blk] visible
        if (wave > blk) {
            unsigned long long m = mcur;
            int base = blk << 6;
            while (m) {
                int j = __builtin_ctzll(m);
                m &= m - 1;
                float4 bj = bx[base + j];
                float w = fmaxf(fminf(box.z, bj.z) - fmaxf(box.x, bj.x), 0.f);
                float h = fmaxf(fminf(box.w, bj.w) - fmaxf(box.y, bj.y), 0.f);
                float inter = w * h;
                float iou = inter / (myar + ar[base + j] - inter + EPSf);
                partial += iou * a_sh[base + j];
            }
        }
        mcur = mnext;
    }
    aval[(size_t)b * KK + t] = fminf(fmaxf(areg, 0.f), 1.f);
}

__global__ __launch_bounds__(256) void best_kernel(
    const float4* __restrict__ pred, const float* __restrict__ gtb, int* win)
{
    int wid = blockIdx.x * 4 + (threadIdx.x >> 6);
    int lane = threadIdx.x & 63;
    int b = wid / GG, g = wid % GG;
    const float* gp = gtb + (b * GG + g) * 4;
    float gx1 = gp[0], gy1 = gp[1], gx2 = gp[2], gy2 = gp[3];
    float ab = fmaxf(gx2 - gx1, 0.f) * fmaxf(gy2 - gy1, 0.f);
    float bi = -1.f; int bk = 0;
    for (int k = lane; k < KK; k += 64) {
        float4 p = pred[b * KK + k];
        float aa = fmaxf(p.z - p.x, 0.f) * fmaxf(p.w - p.y, 0.f);
        float w = fmaxf(fminf(p.z, gx2) - fmaxf(p.x, gx1), 0.f);
        float h = fmaxf(fminf(p.w, gy2) - fmaxf(p.y, gy1), 0.f);
        float inter = w * h;
        float iou = inter / (aa + ab - inter + EPSf);
        if (iou > bi) { bi = iou; bk = k; }   // strict >: first max kept
    }
    for (int o = 32; o; o >>= 1) {
        float oi = __shfl_down(bi, o);
        int ok = __shfl_down(bk, o);
        if (oi > bi || (oi == bi && ok < bk)) { bi = oi; bk = ok; }
    }
    if (lane == 0) win[b * GG + g] = bk;
}

__global__ __launch_bounds__(1024) void bce_final_kernel(
    const float* __restrict__ aval, const int* __restrict__ win,
    const float* __restrict__ accum, float* __restrict__ out)
{
    __shared__ int w_sh[BB * GG];
    __shared__ float bsum[16];
    int t = threadIdx.x;
    if (t < BB * GG) w_sh[t] = win[t];
    __syncthreads();
    float v = 0.f;
    #pragma unroll
    for (int q = 0; q < 4; ++q) {
        int i = q * 1024 + t;
        int b = i >> 10, k = i & 1023;
        float tg = 0.f;
        for (int g = 0; g < GG; ++g) if (w_sh[b * GG + g] == k) tg = 1.f;
        float a = aval[i];
        v += -(tg * logf(a + EPSf) + (1.f - tg) * logf(1.f - a + EPSf));
    }
    for (int o = 32; o; o >>= 1) v += __shfl_down(v, o);
    int wv = t >> 6, ln = t & 63;
    if (ln == 0) bsum[wv] = v;
    __syncthreads();
    if (t == 0) {
        float s = 0.f;
        for (int w = 0; w < 16; ++w) s += bsum[w];
        float nfg = fmaxf(accum[1], 1.f);
        out[0] = accum[0] / (float)(BB * NN)
               + accum[2] / nfg
               + accum[3] / nfg
               + s / (float)(BB * KK);
    }
}

extern "C" void kernel_launch(void* const* d_in, const int* in_sizes, int n_in,
                              void* d_out, int out_size, void* d_ws, size_t ws_size,
                              hipStream_t stream) {
    const float* cls    = (const float*)d_in[0];
    const float* prob   = (const float*)d_in[1];
    const float* bbox2d = (const float*)d_in[2];
    const float* bbox3d = (const float*)d_in[3];
    const float* rois   = (const float*)d_in[4];
    const float* gtb    = (const float*)d_in[5];
    const int*   gtl    = (const int*)d_in[6];
    const float* gt3    = (const float*)d_in[7];
    const float* means  = (const float*)d_in[8];
    const float* stds   = (const float*)d_in[9];
    float* out = (float*)d_out;
    char* ws = (char*)d_ws;

    float*              accum  = (float*)(ws + 0);
    unsigned*           cnt    = (unsigned*)(ws + 32);
    unsigned*           Tbin   = (unsigned*)(ws + 48);
    int*                win    = (int*)(ws + 64);
    unsigned long long* cand   = (unsigned long long*)(ws + 576);
    float*              scores = (float*)(ws + 131648);
    float*              minvT  = (float*)(ws + 131648);   // overlays scores (dead after collect)
    float*              sk     = (float*)(ws + 2159168);
    float4*             pred   = (float4*)(ws + 2175552);
    float*              aval   = (float*)(ws + 2241088);
    float4*             part4  = (float4*)(ws + 2257472);
    unsigned long long* masks  = (unsigned long long*)(ws + 2289152);

    dim3 gBN(NBLKX, BB);
    assign_kernel<<<gBN, dim3(256), 0, stream>>>(cls, prob, bbox2d, bbox3d, rois,
                                                 gtb, gtl, gt3, means, stds,
                                                 scores, part4);
    reduce_partials_kernel<<<dim3(1), dim3(1024), 0, stream>>>(part4, accum);
    hist_thresh_kernel<<<dim3(BB), dim3(1024), 0, stream>>>(scores, Tbin, cnt);
    collect_kernel<<<gBN, dim3(256), 0, stream>>>(scores, Tbin, cnt, cand);
    sort_decode_kernel<<<dim3(BB), dim3(1024), 0, stream>>>(cand, cnt, bbox2d, rois,
                                                            means, stds, sk, pred);
    minv_kernel<<<dim3(BB * 16), dim3(64), 0, stream>>>(pred, minvT);
    pmask_kernel<<<dim3(16, 16, BB), dim3(256), 0, stream>>>(pred, masks);
    solve_kernel<<<dim3(BB), dim3(1024), 0, stream>>>(pred, sk, minvT, masks, aval);
    best_kernel<<<dim3((BB * GG) / 4), dim3(256), 0, stream>>>(pred, gtb, win);
    bce_final_kernel<<<dim3(1), dim3(1024), 0, stream>>>(aval, win, accum, out);
}

// Round 5
// 134.145 us; speedup vs baseline: 5.3143x; 1.1475x over previous
//
#include <hip/hip_runtime.h>
#include <hip/hip_bf16.h>
#include <math.h>

#define BB 4
#define NN 126720
#define GG 32
#define CC 4
#define KK 1024
#define NBIN 16384
#define CANDMAX 4096
#define NBLKX 495            // NN / 256 exactly
#define NBLK (NBLKX * BB)    // 1980
#define NSEG 32              // hist segments per batch (NN/32 = 3960)
#define SEGSZ 3960
#define FG_TH 0.5f
#define NMS_TH 0.4f
#define EPSf 1e-6f

// ---- ws layout (bytes) ----
// cnt u32[4]          @ 0
// Tbin u32[4]         @ 16
// win i32[128]        @ 32      -> 544
// cand u64[4*4096]    @ 576     -> 131648
// scores f32[B*N]     @ 131648  -> 2159168   (minvT f32[64*64*64] overlays @131648, dead after collect)
// sk f32[B*K]         @ 2159168 -> 2175552
// pred float4[B*K]    @ 2175552 -> 2241088
// aval f32[B*K]       @ 2241088 -> 2257472
// part4 float4[NBLK]  @ 2257472 -> 2289152
// masks u64[4*16*1024]@ 2289152 -> 2813440
// ghist u32[4*16384]  @ 2813440 -> 3075584

__device__ inline float sl1(float x) {
    float ax = fabsf(x);
    return ax < 1.f ? 0.5f * ax * ax : ax - 1.f;
}

__global__ __launch_bounds__(256) void assign_kernel(
    const float* __restrict__ cls, const float* __restrict__ prob,
    const float* __restrict__ bbox2d, const float* __restrict__ bbox3d,
    const float* __restrict__ rois, const float* __restrict__ gtb,
    const int* __restrict__ gtl, const float* __restrict__ gt3,
    const float* __restrict__ means, const float* __restrict__ stds,
    float* scores, float4* part4, unsigned* ghist)
{
    __shared__ float s_gtb[GG * 4];
    __shared__ float s_gta[GG];
    __shared__ float s_gt3[GG * 7];
    __shared__ int s_gtl[GG];
    __shared__ float s_ms[22];   // [0..10] means, [11..21] stds
    __shared__ float4 wsum[4];
    int b = blockIdx.y;
    int tid = threadIdx.x;
    if (tid < GG * 4) s_gtb[tid] = gtb[b * GG * 4 + tid];
    if (tid < GG * 7) s_gt3[tid] = gt3[b * GG * 7 + tid];
    if (tid < GG) s_gtl[tid] = gtl[b * GG + tid];
    if (tid < 11) s_ms[tid] = means[tid];
    if (tid >= 32 && tid < 43) s_ms[11 + tid - 32] = stds[tid - 32];
    // zero ghist: blocks (y==0, x<16) each clear 4096 u32 (as 1024 uint4)
    if (b == 0 && blockIdx.x < 16) {
        uint4* gp = (uint4*)(ghist + blockIdx.x * 4096);
        #pragma unroll
        for (int i = 0; i < 4; ++i)
            gp[i * 256 + tid] = make_uint4(0u, 0u, 0u, 0u);
    }
    __syncthreads();
    if (tid >= 64 && tid < 96) {
        int g = tid - 64;
        s_gta[g] = fmaxf(s_gtb[g * 4 + 2] - s_gtb[g * 4 + 0], 0.f)
                 * fmaxf(s_gtb[g * 4 + 3] - s_gtb[g * 4 + 1], 0.f);
    }
    __syncthreads();

    int n = blockIdx.x * 256 + tid;   // always < NN
    float clsv = 0.f, fgv = 0.f, l2v = 0.f, l3v = 0.f;
    {
        const float4 r = *(const float4*)(rois + (size_t)n * 4);
        float aa = fmaxf(r.z - r.x, 0.f) * fmaxf(r.w - r.y, 0.f);
        float best_iou = -1.f; int bg = 0;
        #pragma unroll 4
        for (int g = 0; g < GG; ++g) {
            float gx1 = s_gtb[g * 4 + 0], gy1 = s_gtb[g * 4 + 1];
            float gx2 = s_gtb[g * 4 + 2], gy2 = s_gtb[g * 4 + 3];
            float w = fmaxf(fminf(r.z, gx2) - fmaxf(r.x, gx1), 0.f);
            float h = fmaxf(fminf(r.w, gy2) - fmaxf(r.y, gy1), 0.f);
            float inter = w * h;
            float iou = inter / (aa + s_gta[g] - inter + EPSf);
            if (iou > best_iou) { best_iou = iou; bg = g; }
        }
        bool fg = (best_iou >= FG_TH);

        const float4 c = *(const float4*)(cls + ((size_t)b * NN + n) * 4);
        float m = fmaxf(fmaxf(c.x, c.y), fmaxf(c.z, c.w));
        float lse = m + logf(expf(c.x - m) + expf(c.y - m) + expf(c.z - m) + expf(c.w - m));
        int label = fg ? s_gtl[bg] : 0;
        float csel = (label == 0) ? c.x : (label == 1) ? c.y : (label == 2) ? c.z : c.w;
        clsv = lse - csel;

        if (fg) {
            fgv = 1.f;
            float aw = r.z - r.x, ah = r.w - r.y;
            float acx = r.x + 0.5f * aw, acy = r.y + 0.5f * ah;
            float gx1 = s_gtb[bg * 4 + 0], gy1 = s_gtb[bg * 4 + 1];
            float gx2 = s_gtb[bg * 4 + 2], gy2 = s_gtb[bg * 4 + 3];
            float gw = gx2 - gx1, gh = gy2 - gy1;
            float gcx = gx1 + 0.5f * gw, gcy = gy1 + 0.5f * gh;
            float t0 = (gcx - acx) / (aw + EPSf);
            float t1 = (gcy - acy) / (ah + EPSf);
            float t2 = logf(gw / (aw + EPSf) + EPSf);
            float t3 = logf(gh / (ah + EPSf) + EPSf);
            t0 = (t0 - s_ms[0]) / s_ms[11];
            t1 = (t1 - s_ms[1]) / s_ms[12];
            t2 = (t2 - s_ms[2]) / s_ms[13];
            t3 = (t3 - s_ms[3]) / s_ms[14];
            const float4 d = *(const float4*)(bbox2d + ((size_t)b * NN + n) * 4);
            l2v = sl1(d.x - t0) + sl1(d.y - t1) + sl1(d.z - t2) + sl1(d.w - t3);
            const float* b3 = bbox3d + ((size_t)b * NN + n) * 7;
            for (int i = 0; i < 7; ++i) {
                float t = (s_gt3[bg * 7 + i] - s_ms[4 + i]) / s_ms[15 + i];
                l3v += sl1(b3[i] - t);
            }
        }

        const float4 p = *(const float4*)(prob + ((size_t)b * NN + n) * 4);
        scores[(size_t)b * NN + n] = fmaxf(fmaxf(p.y, p.z), p.w);
    }
    for (int o = 32; o; o >>= 1) {
        clsv += __shfl_down(clsv, o);
        fgv  += __shfl_down(fgv, o);
        l2v  += __shfl_down(l2v, o);
        l3v  += __shfl_down(l3v, o);
    }
    int wave = tid >> 6, lane = tid & 63;
    if (lane == 0) wsum[wave] = make_float4(clsv, fgv, l2v, l3v);
    __syncthreads();
    if (tid == 0) {
        float4 s = wsum[0];
        s.x += wsum[1].x + wsum[2].x + wsum[3].x;
        s.y += wsum[1].y + wsum[2].y + wsum[3].y;
        s.z += wsum[1].z + wsum[2].z + wsum[3].z;
        s.w += wsum[1].w + wsum[2].w + wsum[3].w;
        part4[blockIdx.y * NBLKX + blockIdx.x] = s;
    }
}

// grid (NSEG, BB): per-segment LDS histogram, atomic-merge into ghist
__global__ __launch_bounds__(1024) void hist_kernel(
    const float* __restrict__ scores, unsigned* __restrict__ ghist)
{
    __shared__ unsigned h[NBIN];
    int b = blockIdx.y, seg = blockIdx.x, t = threadIdx.x;
    for (int i = t; i < NBIN; i += 1024) h[i] = 0u;
    __syncthreads();
    const float* sp = scores + (size_t)b * NN + seg * SEGSZ;
    for (int n = t; n < SEGSZ; n += 1024)
        atomicAdd(&h[__float_as_uint(sp[n]) >> 16], 1u);
    __syncthreads();
    unsigned* gh = ghist + b * NBIN;
    for (int i = t; i < NBIN; i += 1024) {
        unsigned v = h[i];
        if (v) atomicAdd(&gh[i], v);
    }
}

// 4 blocks: suffix-scan ghist -> Tbin; zero cnt
__global__ __launch_bounds__(1024) void scan_kernel(
    const unsigned* __restrict__ ghist, unsigned* Tbin, unsigned* cnt)
{
    __shared__ unsigned part[1024];
    int b = blockIdx.x, t = threadIdx.x;
    if (t == 0) cnt[b] = 0u;
    unsigned fine[16]; unsigned s = 0;
    #pragma unroll
    for (int i = 0; i < 16; ++i) { fine[i] = ghist[b * NBIN + t * 16 + i]; s += fine[i]; }
    part[t] = s;
    __syncthreads();
    for (int off = 1; off < 1024; off <<= 1) {
        unsigned v = part[t] + ((t + off < 1024) ? part[t + off] : 0u);
        __syncthreads();
        part[t] = v;
        __syncthreads();
    }
    unsigned nxt = (t == 1023) ? 0u : part[t + 1];
    if (part[t] >= KK && nxt < KK) {
        unsigned cum = nxt;
        unsigned T = (unsigned)(t * 16);
        #pragma unroll
        for (int i = 15; i >= 0; --i) {
            cum += fine[i];
            if (cum >= KK) { T = (unsigned)(t * 16 + i); break; }
        }
        Tbin[b] = T;
    }
}

__global__ __launch_bounds__(256) void collect_kernel(
    const float* __restrict__ scores, const unsigned* __restrict__ Tbin,
    unsigned* cnt, unsigned long long* cand)
{
    __shared__ unsigned wc[4];
    __shared__ unsigned wbase[4];
    int b = blockIdx.y;
    int n = blockIdx.x * 256 + threadIdx.x;
    int wave = threadIdx.x >> 6, lane = threadIdx.x & 63;
    unsigned bits = __float_as_uint(scores[(size_t)b * NN + n]);
    bool pr = ((bits >> 16) >= Tbin[b]);
    unsigned long long mask = __ballot(pr);
    if (lane == 0) wc[wave] = (unsigned)__popcll(mask);
    __syncthreads();
    if (threadIdx.x == 0) {
        unsigned tot = wc[0] + wc[1] + wc[2] + wc[3];
        unsigned base = tot ? atomicAdd(&cnt[b], tot) : 0u;
        for (int w = 0; w < 4; ++w) { wbase[w] = base; base += wc[w]; }
    }
    __syncthreads();
    if (pr) {
        unsigned pos = wbase[wave] + (unsigned)__popcll(mask & ((1ull << lane) - 1ull));
        if (pos < CANDMAX)
            cand[b * CANDMAX + pos] = ((unsigned long long)bits << 32) | (unsigned)(~(unsigned)n);
    }
}

// grid (4, BB): exact-rank selection + decode. Each thread owns candidate
// i = seg*1024 + t; rank = #{j: key_j > key_i} (keys unique); rank<K -> slot.
__global__ __launch_bounds__(1024) void ranksort_kernel(
    const unsigned long long* __restrict__ cand, const unsigned* __restrict__ cnt,
    const float* __restrict__ bbox2d, const float* __restrict__ rois,
    const float* __restrict__ means, const float* __restrict__ stds,
    float* sk, float4* pred)
{
    __shared__ unsigned long long keys[CANDMAX];
    int b = blockIdx.y, seg = blockIdx.x, t = threadIdx.x;
    int c = (int)cnt[b]; if (c > CANDMAX) c = CANDMAX;
    for (int i = t; i < c; i += 1024) keys[i] = cand[b * CANDMAX + i];
    __syncthreads();
    int i = seg * 1024 + t;
    if (i >= c) return;
    unsigned long long mykey = keys[i];
    int r = 0;
    #pragma unroll 4
    for (int j = 0; j < c; ++j) r += (keys[j] > mykey) ? 1 : 0;
    if (r < KK) {
        float sc = __uint_as_float((unsigned)(mykey >> 32));
        unsigned n = ~((unsigned)mykey);
        if (n >= NN) n = NN - 1;
        const float4 d = *(const float4*)(bbox2d + ((size_t)b * NN + n) * 4);
        const float4 rr = *(const float4*)(rois + (size_t)n * 4);
        float d0 = d.x * stds[0] + means[0];
        float d1 = d.y * stds[1] + means[1];
        float d2 = d.z * stds[2] + means[2];
        float d3 = d.w * stds[3] + means[3];
        float aw = rr.z - rr.x, ah = rr.w - rr.y;
        float pcx = rr.x + 0.5f * aw + d0 * aw;
        float pcy = rr.y + 0.5f * ah + d1 * ah;
        float pw = aw * expf(fminf(fmaxf(d2, -4.f), 4.f));
        float ph = ah * expf(fminf(fmaxf(d3, -4.f), 4.f));
        pred[(size_t)b * KK + r] = make_float4(pcx - 0.5f * pw, pcy - 0.5f * ph,
                                               pcx + 0.5f * pw, pcy + 0.5f * ph);
        sk[(size_t)b * KK + r] = sc;
    }
}

// fused: blocks [0,64) minv; [64,1088) pmask; [1088,1120) best-per-GT
__global__ __launch_bounds__(256) void pred_aux_kernel(
    const float4* __restrict__ pred, const float* __restrict__ gtb,
    float* __restrict__ minvT, unsigned long long* __restrict__ masks,
    int* __restrict__ win)
{
    __shared__ float4 box_sh[64];
    __shared__ float ar_sh[64];
    __shared__ float Lr[64 * 68];
    __shared__ float Xt[64 * 65];
    int bid = blockIdx.x;
    int t = threadIdx.x, wave = t >> 6, lane = t & 63;

    if (bid < 64) {
        // ---- (I + L_dd)^{-1} for matrix mId ----
        int mId = bid, b = mId >> 4, blk = mId & 15;
        if (t < 64) {
            float4 v = pred[(size_t)b * KK + blk * 64 + t];
            box_sh[t] = v;
            ar_sh[t] = fmaxf(v.z - v.x, 0.f) * fmaxf(v.w - v.y, 0.f);
        }
        __syncthreads();
        for (int e = t; e < 4096; e += 256) {
            int i = e >> 6, j = e & 63;
            float4 a = box_sh[i], o = box_sh[j];
            float w = fmaxf(fminf(a.z, o.z) - fmaxf(a.x, o.x), 0.f);
            float h = fmaxf(fminf(a.w, o.w) - fmaxf(a.y, o.y), 0.f);
            float inter = w * h;
            float iou = inter / (ar_sh[i] + ar_sh[j] - inter + EPSf);
            Lr[i * 68 + j] = (i > j && iou > NMS_TH) ? iou : 0.f;
        }
        __syncthreads();
        if (t < 64) {
            int cc = t;
            float x[64];
            #pragma unroll
            for (int j = 0; j < 64; ++j) x[j] = (j == cc) ? 1.f : 0.f;
            #pragma unroll
            for (int j = 1; j < 64; ++j) {
                float s0 = 0.f, s1 = 0.f, s2 = 0.f, s3 = 0.f;
                const int jm = (j + 3) & ~3;
                #pragma unroll
                for (int mm = 0; mm < jm; mm += 4) {
                    float4 Lv = *(const float4*)&Lr[j * 68 + mm];
                    s0 += Lv.x * x[mm];
                    s1 += Lv.y * x[mm + 1];
                    s2 += Lv.z * x[mm + 2];
                    s3 += Lv.w * x[mm + 3];
                }
                x[j] -= (s0 + s1) + (s2 + s3);
            }
            #pragma unroll
            for (int j = 0; j < 64; ++j) Xt[j * 65 + cc] = x[j];   // Xt[j][c]=Minv[j][c]
        }
        __syncthreads();
        for (int e = t; e < 4096; e += 256) {
            int j = e >> 6, i = e & 63;
            minvT[((size_t)mId * 64 + j) * 64 + i] = Xt[i * 65 + j];  // minvT[m][j][i]=Minv[i][j]
        }
    } else if (bid < 1088) {
        // ---- sparsity masks ----
        int idx = bid - 64;
        int b = idx >> 8, rem = idx & 255, rb = rem >> 4, cb = rem & 15;
        if (t < 64) {
            float4 rv = pred[(size_t)b * KK + rb * 64 + t];
            box_sh[t] = rv;
            ar_sh[t] = fmaxf(rv.z - rv.x, 0.f) * fmaxf(rv.w - rv.y, 0.f);
        }
        float4 cbox = pred[(size_t)b * KK + cb * 64 + lane];
        float car = fmaxf(cbox.z - cbox.x, 0.f) * fmaxf(cbox.w - cbox.y, 0.f);
        int col = cb * 64 + lane;
        __syncthreads();
        #pragma unroll
        for (int i = 0; i < 16; ++i) {
            int rl = wave * 16 + i;
            int row = rb * 64 + rl;
            float4 rv = box_sh[rl];
            float w = fmaxf(fminf(cbox.z, rv.z) - fmaxf(cbox.x, rv.x), 0.f);
            float h = fmaxf(fminf(cbox.w, rv.w) - fmaxf(cbox.y, rv.y), 0.f);
            float inter = w * h;
            float iou = inter / (car + ar_sh[rl] - inter + EPSf);
            bool p = (col < row) && (iou > NMS_TH);
            unsigned long long m = __ballot(p);
            if (lane == 0) masks[(((size_t)b * 16 + cb) << 10) + row] = m;
        }
    } else {
        // ---- best pred box per GT ----
        int wid = (bid - 1088) * 4 + wave;
        int b = wid >> 5, g = wid & 31;
        const float* gp = gtb + (b * GG + g) * 4;
        float gx1 = gp[0], gy1 = gp[1], gx2 = gp[2], gy2 = gp[3];
        float ab = fmaxf(gx2 - gx1, 0.f) * fmaxf(gy2 - gy1, 0.f);
        float bi = -1.f; int bk = 0;
        for (int k = lane; k < KK; k += 64) {
            float4 p = pred[(size_t)b * KK + k];
            float aa = fmaxf(p.z - p.x, 0.f) * fmaxf(p.w - p.y, 0.f);
            float w = fmaxf(fminf(p.z, gx2) - fmaxf(p.x, gx1), 0.f);
            float h = fmaxf(fminf(p.w, gy2) - fmaxf(p.y, gy1), 0.f);
            float inter = w * h;
            float iou = inter / (aa + ab - inter + EPSf);
            if (iou > bi) { bi = iou; bk = k; }   // strict >: first max kept
        }
        for (int o = 32; o; o >>= 1) {
            float oi = __shfl_down(bi, o);
            int ok = __shfl_down(bk, o);
            if (oi > bi || (oi == bi && ok < bk)) { bi = oi; bk = ok; }
        }
        if (lane == 0) win[b * GG + g] = bk;
    }
}

__global__ __launch_bounds__(1024) void solve_kernel(
    const float4* __restrict__ pred, const float* __restrict__ sk,
    const float* __restrict__ minvT, const unsigned long long* __restrict__ masks,
    float* __restrict__ aval)
{
    __shared__ float4 bx[KK];
    __shared__ float ar[KK];
    __shared__ float a_sh[KK];
    int b = blockIdx.x, t = threadIdx.x;
    int wave = t >> 6, lane = t & 63;
    float4 box = pred[(size_t)b * KK + t];
    float sv = sk[(size_t)b * KK + t];
    float myar = fmaxf(box.z - box.x, 0.f) * fmaxf(box.w - box.y, 0.f);
    bx[t] = box; ar[t] = myar;
    float mrow[64];
    {
        const float* mp = minvT + ((size_t)(b * 16 + wave) * 64) * 64 + lane;
        #pragma unroll
        for (int j = 0; j < 64; ++j) mrow[j] = mp[j * 64];
    }
    const unsigned long long* mbase = masks + (((size_t)b * 16) << 10) + t;
    unsigned long long mcur = mbase[0];
    __syncthreads();
    float partial = 0.f, areg = 0.f;
    for (int blk = 0; blk < 16; ++blk) {
        if (wave == blk) {
            float tval = sv - partial;
            float a0 = 0.f, a1 = 0.f, a2 = 0.f, a3 = 0.f;
            #pragma unroll
            for (int j = 0; j < 64; j += 4) {
                a0 += mrow[j]     * __shfl(tval, j);
                a1 += mrow[j + 1] * __shfl(tval, j + 1);
                a2 += mrow[j + 2] * __shfl(tval, j + 2);
                a3 += mrow[j + 3] * __shfl(tval, j + 3);
            }
            areg = (a0 + a1) + (a2 + a3);
            a_sh[(blk << 6) + lane] = areg;
        }
        unsigned long long mnext = (blk < 15) ? mbase[(size_t)(blk + 1) << 10] : 0ull;
        __syncthreads();
        if (wave > blk) {
            unsigned long long m = mcur;
            int base = blk << 6;
            while (m) {
                int j = __builtin_ctzll(m);
                m &= m - 1;
                float4 bj = bx[base + j];
                float w = fmaxf(fminf(box.z, bj.z) - fmaxf(box.x, bj.x), 0.f);
                float h = fmaxf(fminf(box.w, bj.w) - fmaxf(box.y, bj.y), 0.f);
                float inter = w * h;
                float iou = inter / (myar + ar[base + j] - inter + EPSf);
                partial += iou * a_sh[base + j];
            }
        }
        mcur = mnext;
    }
    aval[(size_t)b * KK + t] = fminf(fmaxf(areg, 0.f), 1.f);
}

// 1 block: reduce part4 (cls/fg/l2/l3) + BCE over aval/win -> out[0]
__global__ __launch_bounds__(1024) void bce_final_kernel(
    const float4* __restrict__ part4, const float* __restrict__ aval,
    const int* __restrict__ win, float* __restrict__ out)
{
    __shared__ int w_sh[BB * GG];
    __shared__ float4 ws4[16];
    __shared__ float wsv[16];
    int t = threadIdx.x;
    if (t < BB * GG) w_sh[t] = win[t];
    __syncthreads();
    float c = 0.f, f = 0.f, l2 = 0.f, l3 = 0.f;
    for (int i = t; i < NBLK; i += 1024) {
        float4 p = part4[i];
        c += p.x; f += p.y; l2 += p.z; l3 += p.w;
    }
    float v = 0.f;
    #pragma unroll
    for (int q = 0; q < 4; ++q) {
        int i = q * 1024 + t;
        int b = i >> 10, k = i & 1023;
        float tg = 0.f;
        for (int g = 0; g < GG; ++g) if (w_sh[b * GG + g] == k) tg = 1.f;
        float a = aval[i];
        v += -(tg * logf(a + EPSf) + (1.f - tg) * logf(1.f - a + EPSf));
    }
    for (int o = 32; o; o >>= 1) {
        c += __shfl_down(c, o); f += __shfl_down(f, o);
        l2 += __shfl_down(l2, o); l3 += __shfl_down(l3, o);
        v += __shfl_down(v, o);
    }
    int wv = t >> 6, ln = t & 63;
    if (ln == 0) { ws4[wv] = make_float4(c, f, l2, l3); wsv[wv] = v; }
    __syncthreads();
    if (t == 0) {
        float4 s = make_float4(0.f, 0.f, 0.f, 0.f); float sv = 0.f;
        for (int w = 0; w < 16; ++w) {
            s.x += ws4[w].x; s.y += ws4[w].y; s.z += ws4[w].z; s.w += ws4[w].w;
            sv += wsv[w];
        }
        float nfg = fmaxf(s.y, 1.f);
        out[0] = s.x / (float)(BB * NN)
               + s.z / nfg
               + s.w / nfg
               + sv / (float)(BB * KK);
    }
}

extern "C" void kernel_launch(void* const* d_in, const int* in_sizes, int n_in,
                              void* d_out, int out_size, void* d_ws, size_t ws_size,
                              hipStream_t stream) {
    const float* cls    = (const float*)d_in[0];
    const float* prob   = (const float*)d_in[1];
    const float* bbox2d = (const float*)d_in[2];
    const float* bbox3d = (const float*)d_in[3];
    const float* rois   = (const float*)d_in[4];
    const float* gtb    = (const float*)d_in[5];
    const int*   gtl    = (const int*)d_in[6];
    const float* gt3    = (const float*)d_in[7];
    const float* means  = (const float*)d_in[8];
    const float* stds   = (const float*)d_in[9];
    float* out = (float*)d_out;
    char* ws = (char*)d_ws;

    unsigned*           cnt    = (unsigned*)(ws + 0);
    unsigned*           Tbin   = (unsigned*)(ws + 16);
    int*                win    = (int*)(ws + 32);
    unsigned long long* cand   = (unsigned long long*)(ws + 576);
    float*              scores = (float*)(ws + 131648);
    float*              minvT  = (float*)(ws + 131648);   // overlays scores (dead after collect)
    float*              sk     = (float*)(ws + 2159168);
    float4*             pred   = (float4*)(ws + 2175552);
    float*              aval   = (float*)(ws + 2241088);
    float4*             part4  = (float4*)(ws + 2257472);
    unsigned long long* masks  = (unsigned long long*)(ws + 2289152);
    unsigned*           ghist  = (unsigned*)(ws + 2813440);

    dim3 gBN(NBLKX, BB);
    assign_kernel<<<gBN, dim3(256), 0, stream>>>(cls, prob, bbox2d, bbox3d, rois,
                                                 gtb, gtl, gt3, means, stds,
                                                 scores, part4, ghist);
    hist_kernel<<<dim3(NSEG, BB), dim3(1024), 0, stream>>>(scores, ghist);
    scan_kernel<<<dim3(BB), dim3(1024), 0, stream>>>(ghist, Tbin, cnt);
    collect_kernel<<<gBN, dim3(256), 0, stream>>>(scores, Tbin, cnt, cand);
    ranksort_kernel<<<dim3(4, BB), dim3(1024), 0, stream>>>(cand, cnt, bbox2d, rois,
                                                            means, stds, sk, pred);
    pred_aux_kernel<<<dim3(1120), dim3(256), 0, stream>>>(pred, gtb, minvT, masks, win);
    solve_kernel<<<dim3(BB), dim3(1024), 0, stream>>>(pred, sk, minvT, masks, aval);
    bce_final_kernel<<<dim3(1), dim3(1024), 0, stream>>>(part4, aval, win, out);
}

// Round 6
// 106.318 us; speedup vs baseline: 6.7052x; 1.2617x over previous
//
#include <hip/hip_runtime.h>
#include <hip/hip_bf16.h>
#include <math.h>

#define BB 4
#define NN 126720
#define GG 32
#define CC 4
#define KK 1024
#define NBIN 16384
#define CANDMAX 4096
#define NBLKX 495            // NN / 256 exactly
#define NBLK (NBLKX * BB)    // 1980
#define NSEG 32              // hist segments per batch (NN/32 = 3960)
#define SEGSZ 3960
#define FG_TH 0.5f
#define NMS_TH 0.4f
#define EPSf 1e-6f

// ---- ws layout (bytes) ----
// cnt u32[4]          @ 0
// Tbin u32[4]         @ 16
// win i32[128]        @ 32      -> 544
// cand u64[4*4096]    @ 576     -> 131648
// scores f32[B*N]     @ 131648  -> 2159168   (minvT f32[64*64*64] overlays @131648, dead after collect)
// sk f32[B*K]         @ 2159168 -> 2175552
// pred float4[B*K]    @ 2175552 -> 2241088
// aval f32[B*K]       @ 2241088 -> 2257472
// part4 float4[NBLK]  @ 2257472 -> 2289152
// masks u64[4*16*1024]@ 2289152 -> 2813440
// ghist u32[4*16384]  @ 2813440 -> 3075584

__device__ inline float sl1(float x) {
    float ax = fabsf(x);
    return ax < 1.f ? 0.5f * ax * ax : ax - 1.f;
}

__global__ __launch_bounds__(256) void assign_kernel(
    const float* __restrict__ cls, const float* __restrict__ prob,
    const float* __restrict__ bbox2d, const float* __restrict__ bbox3d,
    const float* __restrict__ rois, const float* __restrict__ gtb,
    const int* __restrict__ gtl, const float* __restrict__ gt3,
    const float* __restrict__ means, const float* __restrict__ stds,
    float* scores, float4* part4, unsigned* ghist)
{
    __shared__ float s_gtb[GG * 4];
    __shared__ float s_gta[GG];
    __shared__ float s_gt3[GG * 7];
    __shared__ int s_gtl[GG];
    __shared__ float s_ms[22];   // [0..10] means, [11..21] stds
    __shared__ float4 wsum[4];
    int b = blockIdx.y;
    int tid = threadIdx.x;
    if (tid < GG * 4) s_gtb[tid] = gtb[b * GG * 4 + tid];
    if (tid < GG * 7) s_gt3[tid] = gt3[b * GG * 7 + tid];
    if (tid < GG) s_gtl[tid] = gtl[b * GG + tid];
    if (tid < 11) s_ms[tid] = means[tid];
    if (tid >= 32 && tid < 43) s_ms[11 + tid - 32] = stds[tid - 32];
    // zero ghist: blocks (y==0, x<16) each clear 4096 u32 (as 1024 uint4)
    if (b == 0 && blockIdx.x < 16) {
        uint4* gp = (uint4*)(ghist + blockIdx.x * 4096);
        #pragma unroll
        for (int i = 0; i < 4; ++i)
            gp[i * 256 + tid] = make_uint4(0u, 0u, 0u, 0u);
    }
    __syncthreads();
    if (tid >= 64 && tid < 96) {
        int g = tid - 64;
        s_gta[g] = fmaxf(s_gtb[g * 4 + 2] - s_gtb[g * 4 + 0], 0.f)
                 * fmaxf(s_gtb[g * 4 + 3] - s_gtb[g * 4 + 1], 0.f);
    }
    __syncthreads();

    int n = blockIdx.x * 256 + tid;   // always < NN
    float clsv = 0.f, fgv = 0.f, l2v = 0.f, l3v = 0.f;
    {
        const float4 r = *(const float4*)(rois + (size_t)n * 4);
        float aa = fmaxf(r.z - r.x, 0.f) * fmaxf(r.w - r.y, 0.f);
        float best_iou = -1.f; int bg = 0;
        #pragma unroll 4
        for (int g = 0; g < GG; ++g) {
            float gx1 = s_gtb[g * 4 + 0], gy1 = s_gtb[g * 4 + 1];
            float gx2 = s_gtb[g * 4 + 2], gy2 = s_gtb[g * 4 + 3];
            float w = fmaxf(fminf(r.z, gx2) - fmaxf(r.x, gx1), 0.f);
            float h = fmaxf(fminf(r.w, gy2) - fmaxf(r.y, gy1), 0.f);
            float inter = w * h;
            float iou = inter / (aa + s_gta[g] - inter + EPSf);
            if (iou > best_iou) { best_iou = iou; bg = g; }
        }
        bool fg = (best_iou >= FG_TH);

        const float4 c = *(const float4*)(cls + ((size_t)b * NN + n) * 4);
        float m = fmaxf(fmaxf(c.x, c.y), fmaxf(c.z, c.w));
        float lse = m + logf(expf(c.x - m) + expf(c.y - m) + expf(c.z - m) + expf(c.w - m));
        int label = fg ? s_gtl[bg] : 0;
        float csel = (label == 0) ? c.x : (label == 1) ? c.y : (label == 2) ? c.z : c.w;
        clsv = lse - csel;

        if (fg) {
            fgv = 1.f;
            float aw = r.z - r.x, ah = r.w - r.y;
            float acx = r.x + 0.5f * aw, acy = r.y + 0.5f * ah;
            float gx1 = s_gtb[bg * 4 + 0], gy1 = s_gtb[bg * 4 + 1];
            float gx2 = s_gtb[bg * 4 + 2], gy2 = s_gtb[bg * 4 + 3];
            float gw = gx2 - gx1, gh = gy2 - gy1;
            float gcx = gx1 + 0.5f * gw, gcy = gy1 + 0.5f * gh;
            float t0 = (gcx - acx) / (aw + EPSf);
            float t1 = (gcy - acy) / (ah + EPSf);
            float t2 = logf(gw / (aw + EPSf) + EPSf);
            float t3 = logf(gh / (ah + EPSf) + EPSf);
            t0 = (t0 - s_ms[0]) / s_ms[11];
            t1 = (t1 - s_ms[1]) / s_ms[12];
            t2 = (t2 - s_ms[2]) / s_ms[13];
            t3 = (t3 - s_ms[3]) / s_ms[14];
            const float4 d = *(const float4*)(bbox2d + ((size_t)b * NN + n) * 4);
            l2v = sl1(d.x - t0) + sl1(d.y - t1) + sl1(d.z - t2) + sl1(d.w - t3);
            const float* b3 = bbox3d + ((size_t)b * NN + n) * 7;
            for (int i = 0; i < 7; ++i) {
                float t = (s_gt3[bg * 7 + i] - s_ms[4 + i]) / s_ms[15 + i];
                l3v += sl1(b3[i] - t);
            }
        }

        const float4 p = *(const float4*)(prob + ((size_t)b * NN + n) * 4);
        scores[(size_t)b * NN + n] = fmaxf(fmaxf(p.y, p.z), p.w);
    }
    for (int o = 32; o; o >>= 1) {
        clsv += __shfl_down(clsv, o);
        fgv  += __shfl_down(fgv, o);
        l2v  += __shfl_down(l2v, o);
        l3v  += __shfl_down(l3v, o);
    }
    int wave = tid >> 6, lane = tid & 63;
    if (lane == 0) wsum[wave] = make_float4(clsv, fgv, l2v, l3v);
    __syncthreads();
    if (tid == 0) {
        float4 s = wsum[0];
        s.x += wsum[1].x + wsum[2].x + wsum[3].x;
        s.y += wsum[1].y + wsum[2].y + wsum[3].y;
        s.z += wsum[1].z + wsum[2].z + wsum[3].z;
        s.w += wsum[1].w + wsum[2].w + wsum[3].w;
        part4[blockIdx.y * NBLKX + blockIdx.x] = s;
    }
}

// grid (NSEG, BB): per-segment LDS histogram, atomic-merge into ghist
__global__ __launch_bounds__(1024) void hist_kernel(
    const float* __restrict__ scores, unsigned* __restrict__ ghist)
{
    __shared__ unsigned h[NBIN];
    int b = blockIdx.y, seg = blockIdx.x, t = threadIdx.x;
    for (int i = t; i < NBIN; i += 1024) h[i] = 0u;
    __syncthreads();
    const float* sp = scores + (size_t)b * NN + seg * SEGSZ;
    for (int n = t; n < SEGSZ; n += 1024)
        atomicAdd(&h[__float_as_uint(sp[n]) >> 16], 1u);
    __syncthreads();
    unsigned* gh = ghist + b * NBIN;
    for (int i = t; i < NBIN; i += 1024) {
        unsigned v = h[i];
        if (v) atomicAdd(&gh[i], v);
    }
}

// 4 blocks: suffix-scan ghist -> Tbin; zero cnt
__global__ __launch_bounds__(1024) void scan_kernel(
    const unsigned* __restrict__ ghist, unsigned* Tbin, unsigned* cnt)
{
    __shared__ unsigned part[1024];
    int b = blockIdx.x, t = threadIdx.x;
    if (t == 0) cnt[b] = 0u;
    unsigned fine[16]; unsigned s = 0;
    #pragma unroll
    for (int i = 0; i < 16; ++i) { fine[i] = ghist[b * NBIN + t * 16 + i]; s += fine[i]; }
    part[t] = s;
    __syncthreads();
    for (int off = 1; off < 1024; off <<= 1) {
        unsigned v = part[t] + ((t + off < 1024) ? part[t + off] : 0u);
        __syncthreads();
        part[t] = v;
        __syncthreads();
    }
    unsigned nxt = (t == 1023) ? 0u : part[t + 1];
    if (part[t] >= KK && nxt < KK) {
        unsigned cum = nxt;
        unsigned T = (unsigned)(t * 16);
        #pragma unroll
        for (int i = 15; i >= 0; --i) {
            cum += fine[i];
            if (cum >= KK) { T = (unsigned)(t * 16 + i); break; }
        }
        Tbin[b] = T;
    }
}

__global__ __launch_bounds__(256) void collect_kernel(
    const float* __restrict__ scores, const unsigned* __restrict__ Tbin,
    unsigned* cnt, unsigned long long* cand)
{
    __shared__ unsigned wc[4];
    __shared__ unsigned wbase[4];
    int b = blockIdx.y;
    int n = blockIdx.x * 256 + threadIdx.x;
    int wave = threadIdx.x >> 6, lane = threadIdx.x & 63;
    unsigned bits = __float_as_uint(scores[(size_t)b * NN + n]);
    bool pr = ((bits >> 16) >= Tbin[b]);
    unsigned long long mask = __ballot(pr);
    if (lane == 0) wc[wave] = (unsigned)__popcll(mask);
    __syncthreads();
    if (threadIdx.x == 0) {
        unsigned tot = wc[0] + wc[1] + wc[2] + wc[3];
        unsigned base = tot ? atomicAdd(&cnt[b], tot) : 0u;
        for (int w = 0; w < 4; ++w) { wbase[w] = base; base += wc[w]; }
    }
    __syncthreads();
    if (pr) {
        unsigned pos = wbase[wave] + (unsigned)__popcll(mask & ((1ull << lane) - 1ull));
        if (pos < CANDMAX)
            cand[b * CANDMAX + pos] = ((unsigned long long)bits << 32) | (unsigned)(~(unsigned)n);
    }
}

// grid (16, BB): exact-rank selection + decode, 4-way cooperative.
// Candidate i = seg*256 + (t>>2); collaborator m = t&3 scans j = m, m+4, ...
// rank = #{j: key_j > key_i} (keys unique); rank<K -> slot.
__global__ __launch_bounds__(1024) void ranksort_kernel(
    const unsigned long long* __restrict__ cand, const unsigned* __restrict__ cnt,
    const float* __restrict__ bbox2d, const float* __restrict__ rois,
    const float* __restrict__ means, const float* __restrict__ stds,
    float* sk, float4* pred)
{
    __shared__ unsigned long long keys[CANDMAX];
    int b = blockIdx.y, seg = blockIdx.x, t = threadIdx.x;
    int c = (int)cnt[b]; if (c > CANDMAX) c = CANDMAX;
    for (int i = t; i < c; i += 1024) keys[i] = cand[b * CANDMAX + i];
    __syncthreads();
    int i = seg * 256 + (t >> 2);
    if (i >= c) return;
    unsigned long long mykey = keys[i];
    int r = 0;
    {
        int m = t & 3;
        int j = m;
        for (; j + 12 < c; j += 16) {
            r += (keys[j]      > mykey) ? 1 : 0;
            r += (keys[j + 4]  > mykey) ? 1 : 0;
            r += (keys[j + 8]  > mykey) ? 1 : 0;
            r += (keys[j + 12] > mykey) ? 1 : 0;
        }
        for (; j < c; j += 4) r += (keys[j] > mykey) ? 1 : 0;
    }
    r += __shfl_xor(r, 1);
    r += __shfl_xor(r, 2);
    if ((t & 3) == 0 && r < KK) {
        float sc = __uint_as_float((unsigned)(mykey >> 32));
        unsigned n = ~((unsigned)mykey);
        if (n >= NN) n = NN - 1;
        const float4 d = *(const float4*)(bbox2d + ((size_t)b * NN + n) * 4);
        const float4 rr = *(const float4*)(rois + (size_t)n * 4);
        float d0 = d.x * stds[0] + means[0];
        float d1 = d.y * stds[1] + means[1];
        float d2 = d.z * stds[2] + means[2];
        float d3 = d.w * stds[3] + means[3];
        float aw = rr.z - rr.x, ah = rr.w - rr.y;
        float pcx = rr.x + 0.5f * aw + d0 * aw;
        float pcy = rr.y + 0.5f * ah + d1 * ah;
        float pw = aw * expf(fminf(fmaxf(d2, -4.f), 4.f));
        float ph = ah * expf(fminf(fmaxf(d3, -4.f), 4.f));
        pred[(size_t)b * KK + r] = make_float4(pcx - 0.5f * pw, pcy - 0.5f * ph,
                                               pcx + 0.5f * pw, pcy + 0.5f * ph);
        sk[(size_t)b * KK + r] = sc;
    }
}

// fused: blocks [0,64) minv; [64,1088) pmask; [1088,1120) best-per-GT
__global__ __launch_bounds__(256) void pred_aux_kernel(
    const float4* __restrict__ pred, const float* __restrict__ gtb,
    float* __restrict__ minvT, unsigned long long* __restrict__ masks,
    int* __restrict__ win)
{
    __shared__ float4 box_sh[64];
    __shared__ float ar_sh[64];
    __shared__ float Lr[64 * 68];
    __shared__ float Xt[64 * 65];
    int bid = blockIdx.x;
    int t = threadIdx.x, wave = t >> 6, lane = t & 63;

    if (bid < 64) {
        // ---- (I + L_dd)^{-1} for matrix mId ----
        int mId = bid, b = mId >> 4, blk = mId & 15;
        if (t < 64) {
            float4 v = pred[(size_t)b * KK + blk * 64 + t];
            box_sh[t] = v;
            ar_sh[t] = fmaxf(v.z - v.x, 0.f) * fmaxf(v.w - v.y, 0.f);
        }
        __syncthreads();
        for (int e = t; e < 4096; e += 256) {
            int i = e >> 6, j = e & 63;
            float4 a = box_sh[i], o = box_sh[j];
            float w = fmaxf(fminf(a.z, o.z) - fmaxf(a.x, o.x), 0.f);
            float h = fmaxf(fminf(a.w, o.w) - fmaxf(a.y, o.y), 0.f);
            float inter = w * h;
            float iou = inter / (ar_sh[i] + ar_sh[j] - inter + EPSf);
            Lr[i * 68 + j] = (i > j && iou > NMS_TH) ? iou : 0.f;
        }
        __syncthreads();
        if (t < 64) {
            int cc = t;
            float x[64];
            #pragma unroll
            for (int j = 0; j < 64; ++j) x[j] = (j == cc) ? 1.f : 0.f;
            #pragma unroll
            for (int j = 1; j < 64; ++j) {
                float s0 = 0.f, s1 = 0.f, s2 = 0.f, s3 = 0.f;
                const int jm = (j + 3) & ~3;
                #pragma unroll
                for (int mm = 0; mm < jm; mm += 4) {
                    float4 Lv = *(const float4*)&Lr[j * 68 + mm];
                    s0 += Lv.x * x[mm];
                    s1 += Lv.y * x[mm + 1];
                    s2 += Lv.z * x[mm + 2];
                    s3 += Lv.w * x[mm + 3];
                }
                x[j] -= (s0 + s1) + (s2 + s3);
            }
            #pragma unroll
            for (int j = 0; j < 64; ++j) Xt[j * 65 + cc] = x[j];   // Xt[j][c]=Minv[j][c]
        }
        __syncthreads();
        for (int e = t; e < 4096; e += 256) {
            int j = e >> 6, i = e & 63;
            minvT[((size_t)mId * 64 + j) * 64 + i] = Xt[i * 65 + j];  // minvT[m][j][i]=Minv[i][j]
        }
    } else if (bid < 1088) {
        // ---- sparsity masks ----
        int idx = bid - 64;
        int b = idx >> 8, rem = idx & 255, rb = rem >> 4, cb = rem & 15;
        if (t < 64) {
            float4 rv = pred[(size_t)b * KK + rb * 64 + t];
            box_sh[t] = rv;
            ar_sh[t] = fmaxf(rv.z - rv.x, 0.f) * fmaxf(rv.w - rv.y, 0.f);
        }
        float4 cbox = pred[(size_t)b * KK + cb * 64 + lane];
        float car = fmaxf(cbox.z - cbox.x, 0.f) * fmaxf(cbox.w - cbox.y, 0.f);
        int col = cb * 64 + lane;
        __syncthreads();
        #pragma unroll
        for (int i = 0; i < 16; ++i) {
            int rl = wave * 16 + i;
            int row = rb * 64 + rl;
            float4 rv = box_sh[rl];
            float w = fmaxf(fminf(cbox.z, rv.z) - fmaxf(cbox.x, rv.x), 0.f);
            float h = fmaxf(fminf(cbox.w, rv.w) - fmaxf(cbox.y, rv.y), 0.f);
            float inter = w * h;
            float iou = inter / (car + ar_sh[rl] - inter + EPSf);
            bool p = (col < row) && (iou > NMS_TH);
            unsigned long long m = __ballot(p);
            if (lane == 0) masks[(((size_t)b * 16 + cb) << 10) + row] = m;
        }
    } else {
        // ---- best pred box per GT ----
        int wid = (bid - 1088) * 4 + wave;
        int b = wid >> 5, g = wid & 31;
        const float* gp = gtb + (b * GG + g) * 4;
        float gx1 = gp[0], gy1 = gp[1], gx2 = gp[2], gy2 = gp[3];
        float ab = fmaxf(gx2 - gx1, 0.f) * fmaxf(gy2 - gy1, 0.f);
        float bi = -1.f; int bk = 0;
        for (int k = lane; k < KK; k += 64) {
            float4 p = pred[(size_t)b * KK + k];
            float aa = fmaxf(p.z - p.x, 0.f) * fmaxf(p.w - p.y, 0.f);
            float w = fmaxf(fminf(p.z, gx2) - fmaxf(p.x, gx1), 0.f);
            float h = fmaxf(fminf(p.w, gy2) - fmaxf(p.y, gy1), 0.f);
            float inter = w * h;
            float iou = inter / (aa + ab - inter + EPSf);
            if (iou > bi) { bi = iou; bk = k; }   // strict >: first max kept
        }
        for (int o = 32; o; o >>= 1) {
            float oi = __shfl_down(bi, o);
            int ok = __shfl_down(bk, o);
            if (oi > bi || (oi == bi && ok < bk)) { bi = oi; bk = ok; }
        }
        if (lane == 0) win[b * GG + g] = bk;
    }
}

__global__ __launch_bounds__(1024) void solve_kernel(
    const float4* __restrict__ pred, const float* __restrict__ sk,
    const float* __restrict__ minvT, const unsigned long long* __restrict__ masks,
    float* __restrict__ aval)
{
    __shared__ float4 bx[KK];
    __shared__ float ar[KK];
    __shared__ float a_sh[KK];
    int b = blockIdx.x, t = threadIdx.x;
    int wave = t >> 6, lane = t & 63;
    float4 box = pred[(size_t)b * KK + t];
    float sv = sk[(size_t)b * KK + t];
    float myar = fmaxf(box.z - box.x, 0.f) * fmaxf(box.w - box.y, 0.f);
    bx[t] = box; ar[t] = myar;
    float mrow[64];
    {
        const float* mp = minvT + ((size_t)(b * 16 + wave) * 64) * 64 + lane;
        #pragma unroll
        for (int j = 0; j < 64; ++j) mrow[j] = mp[j * 64];
    }
    const unsigned long long* mbase = masks + (((size_t)b * 16) << 10) + t;
    unsigned long long mcur = mbase[0];
    __syncthreads();
    float partial = 0.f, areg = 0.f;
    for (int blk = 0; blk < 16; ++blk) {
        if (wave == blk) {
            float tval = sv - partial;
            float a0 = 0.f, a1 = 0.f, a2 = 0.f, a3 = 0.f;
            #pragma unroll
            for (int j = 0; j < 64; j += 4) {
                a0 += mrow[j]     * __shfl(tval, j);
                a1 += mrow[j + 1] * __shfl(tval, j + 1);
                a2 += mrow[j + 2] * __shfl(tval, j + 2);
                a3 += mrow[j + 3] * __shfl(tval, j + 3);
            }
            areg = (a0 + a1) + (a2 + a3);
            a_sh[(blk << 6) + lane] = areg;
        }
        unsigned long long mnext = (blk < 15) ? mbase[(size_t)(blk + 1) << 10] : 0ull;
        __syncthreads();
        if (wave > blk) {
            unsigned long long m = mcur;
            int base = blk << 6;
            while (m) {
                int j = __builtin_ctzll(m);
                m &= m - 1;
                float4 bj = bx[base + j];
                float w = fmaxf(fminf(box.z, bj.z) - fmaxf(box.x, bj.x), 0.f);
                float h = fmaxf(fminf(box.w, bj.w) - fmaxf(box.y, bj.y), 0.f);
                float inter = w * h;
                float iou = inter / (myar + ar[base + j] - inter + EPSf);
                partial += iou * a_sh[base + j];
            }
        }
        mcur = mnext;
    }
    aval[(size_t)b * KK + t] = fminf(fmaxf(areg, 0.f), 1.f);
}

// 1 block: reduce part4 (cls/fg/l2/l3) + BCE over aval/win -> out[0]
__global__ __launch_bounds__(1024) void bce_final_kernel(
    const float4* __restrict__ part4, const float* __restrict__ aval,
    const int* __restrict__ win, float* __restrict__ out)
{
    __shared__ int w_sh[BB * GG];
    __shared__ float4 ws4[16];
    __shared__ float wsv[16];
    int t = threadIdx.x;
    if (t < BB * GG) w_sh[t] = win[t];
    __syncthreads();
    float c = 0.f, f = 0.f, l2 = 0.f, l3 = 0.f;
    for (int i = t; i < NBLK; i += 1024) {
        float4 p = part4[i];
        c += p.x; f += p.y; l2 += p.z; l3 += p.w;
    }
    float v = 0.f;
    #pragma unroll
    for (int q = 0; q < 4; ++q) {
        int i = q * 1024 + t;
        int b = i >> 10, k = i & 1023;
        float tg = 0.f;
        for (int g = 0; g < GG; ++g) if (w_sh[b * GG + g] == k) tg = 1.f;
        float a = aval[i];
        v += -(tg * logf(a + EPSf) + (1.f - tg) * logf(1.f - a + EPSf));
    }
    for (int o = 32; o; o >>= 1) {
        c += __shfl_down(c, o); f += __shfl_down(f, o);
        l2 += __shfl_down(l2, o); l3 += __shfl_down(l3, o);
        v += __shfl_down(v, o);
    }
    int wv = t >> 6, ln = t & 63;
    if (ln == 0) { ws4[wv] = make_float4(c, f, l2, l3); wsv[wv] = v; }
    __syncthreads();
    if (t == 0) {
        float4 s = make_float4(0.f, 0.f, 0.f, 0.f); float sv = 0.f;
        for (int w = 0; w < 16; ++w) {
            s.x += ws4[w].x; s.y += ws4[w].y; s.z += ws4[w].z; s.w += ws4[w].w;
            sv += wsv[w];
        }
        float nfg = fmaxf(s.y, 1.f);
        out[0] = s.x / (float)(BB * NN)
               + s.z / nfg
               + s.w / nfg
               + sv / (float)(BB * KK);
    }
}

extern "C" void kernel_launch(void* const* d_in, const int* in_sizes, int n_in,
                              void* d_out, int out_size, void* d_ws, size_t ws_size,
                              hipStream_t stream) {
    const float* cls    = (const float*)d_in[0];
    const float* prob   = (const float*)d_in[1];
    const float* bbox2d = (const float*)d_in[2];
    const float* bbox3d = (const float*)d_in[3];
    const float* rois   = (const float*)d_in[4];
    const float* gtb    = (const float*)d_in[5];
    const int*   gtl    = (const int*)d_in[6];
    const float* gt3    = (const float*)d_in[7];
    const float* means  = (const float*)d_in[8];
    const float* stds   = (const float*)d_in[9];
    float* out = (float*)d_out;
    char* ws = (char*)d_ws;

    unsigned*           cnt    = (unsigned*)(ws + 0);
    unsigned*           Tbin   = (unsigned*)(ws + 16);
    int*                win    = (int*)(ws + 32);
    unsigned long long* cand   = (unsigned long long*)(ws + 576);
    float*              scores = (float*)(ws + 131648);
    float*              minvT  = (float*)(ws + 131648);   // overlays scores (dead after collect)
    float*              sk     = (float*)(ws + 2159168);
    float4*             pred   = (float4*)(ws + 2175552);
    float*              aval   = (float*)(ws + 2241088);
    float4*             part4  = (float4*)(ws + 2257472);
    unsigned long long* masks  = (unsigned long long*)(ws + 2289152);
    unsigned*           ghist  = (unsigned*)(ws + 2813440);

    dim3 gBN(NBLKX, BB);
    assign_kernel<<<gBN, dim3(256), 0, stream>>>(cls, prob, bbox2d, bbox3d, rois,
                                                 gtb, gtl, gt3, means, stds,
                                                 scores, part4, ghist);
    hist_kernel<<<dim3(NSEG, BB), dim3(1024), 0, stream>>>(scores, ghist);
    scan_kernel<<<dim3(BB), dim3(1024), 0, stream>>>(ghist, Tbin, cnt);
    collect_kernel<<<gBN, dim3(256), 0, stream>>>(scores, Tbin, cnt, cand);
    ranksort_kernel<<<dim3(16, BB), dim3(1024), 0, stream>>>(cand, cnt, bbox2d, rois,
                                                             means, stds, sk, pred);
    pred_aux_kernel<<<dim3(1120), dim3(256), 0, stream>>>(pred, gtb, minvT, masks, win);
    solve_kernel<<<dim3(BB), dim3(1024), 0, stream>>>(pred, sk, minvT, masks, aval);
    bce_final_kernel<<<dim3(1), dim3(1024), 0, stream>>>(part4, aval, win, out);
}